// Round 6
// baseline (478.627 us; speedup 1.0000x reference)
//
#include <hip/hip_runtime.h>
#include <hip/hip_bf16.h>
#include <cstdint>

typedef unsigned short u16;
typedef short s16x8 __attribute__((ext_vector_type(8)));
typedef short s16x4 __attribute__((ext_vector_type(4)));
typedef float f32x4 __attribute__((ext_vector_type(4)));

#define C_DIM 384
#define NHEAD 12
#define HD    32
#define NTOK  343     // tokens per window (7^3)
#define NWIN  64
#define LTOT  21952   // 28^3
#define SIDE  28

__device__ __forceinline__ float u2f(u16 u) {
    return __uint_as_float(((unsigned int)u) << 16);
}
__device__ __forceinline__ u16 f2b(float f) {
    unsigned int u = __float_as_uint(f);
    return (u16)((u + 0x7fffu + ((u >> 16) & 1u)) >> 16);   // RNE
}
__device__ __forceinline__ float exp2_hw(float x) {
    float r;
    asm("v_exp_f32 %0, %1" : "=v"(r) : "v"(x));
    return r;
}
// pack two f32 -> two bf16 (RNE) in one op
__device__ __forceinline__ unsigned int pk_bf16(float lo, float hi) {
    unsigned int r;
    asm("v_cvt_pk_bf16_f32 %0, %1, %2" : "=v"(r) : "v"(lo), "v"(hi));
    return r;
}
// gelu tanh-approx: 0.5x(1+tanh(z)) == x / (1 + 2^(-2z*log2e))
__device__ __forceinline__ float gelu_fast(float x) {
    float e = exp2_hw(-2.3022083f * (x + 0.044715f * x * x * x));
    return x * __builtin_amdgcn_rcpf(1.f + e);
}

// ---------------------------------------------------------------------------
// Weight transpose + f32->bf16: Wt[n][k] = bf16(W[k][n]).  W is KxN row-major.
// ---------------------------------------------------------------------------
__global__ __launch_bounds__(256) void k_wt(
    const float* __restrict__ W, u16* __restrict__ Wt, int K, int N)
{
    __shared__ float T[64][65];
    int k0 = blockIdx.x * 64, n0 = blockIdx.y * 64;
    int t = threadIdx.x;
    int c = t & 63, rg = t >> 6;
#pragma unroll
    for (int i = 0; i < 16; i++) {
        int r = rg * 16 + i;
        T[r][c] = W[(size_t)(k0 + r) * N + n0 + c];
    }
    __syncthreads();
    int k = t & 63, ng = t >> 6;
#pragma unroll
    for (int i = 0; i < 16; i++) {
        int n = ng * 16 + i;
        Wt[(size_t)(n0 + n) * K + k0 + k] = f2b(T[k][n]);
    }
}

// Same, but the k (contraction) index is pi-permuted within each 128-block:
// j = k%128 = ct*16+n  ->  j' = 32*(ct>>1) + 2*n + (ct&1).
// Used for w2 so mlp1 can store h1 in pair-packed column order.
__global__ __launch_bounds__(256) void k_wt_pi(
    const float* __restrict__ W, u16* __restrict__ Wt, int K, int N)
{
    __shared__ float T[64][65];
    int k0 = blockIdx.x * 64, n0 = blockIdx.y * 64;
    int t = threadIdx.x;
    int c = t & 63, rg = t >> 6;
#pragma unroll
    for (int i = 0; i < 16; i++) {
        int r = rg * 16 + i;
        T[r][c] = W[(size_t)(k0 + r) * N + n0 + c];
    }
    __syncthreads();
    int k = t & 63, ng = t >> 6;
    int kg = k0 + k;
    int j = kg & 127, ct = j >> 4, nn = j & 15;
    int kp = (kg & ~127) | ((ct >> 1) << 5) | (nn << 1) | (ct & 1);
#pragma unroll
    for (int i = 0; i < 16; i++) {
        int n = ng * 16 + i;
        Wt[(size_t)(n0 + n) * K + kp] = f2b(T[k][n]);
    }
}

// ---------------------------------------------------------------------------
// Kernel 1: dual LayerNorm + window partition -> bf16; also res = bf16(skip+xup)
// ---------------------------------------------------------------------------
__global__ __launch_bounds__(256) void k_lnprep(
    const float* __restrict__ skip, const float* __restrict__ xup,
    const float* __restrict__ g, const float* __restrict__ bta,
    u16* __restrict__ skW, u16* __restrict__ qW, u16* __restrict__ res)
{
    int t = blockIdx.x * 4 + (threadIdx.x >> 6);
    int lane = threadIdx.x & 63;
    const float* ps = skip + (size_t)t * C_DIM;
    const float* px = xup + (size_t)t * C_DIM;
    float vs[6], vx[6];
    float s1 = 0.f, s2 = 0.f, x1 = 0.f, x2 = 0.f;
#pragma unroll
    for (int j = 0; j < 6; j++) {
        float a = ps[lane + j * 64];
        float b = px[lane + j * 64];
        vs[j] = a; vx[j] = b;
        s1 += a; s2 += a * a; x1 += b; x2 += b * b;
    }
#pragma unroll
    for (int off = 32; off; off >>= 1) {
        s1 += __shfl_xor(s1, off);
        s2 += __shfl_xor(s2, off);
        x1 += __shfl_xor(x1, off);
        x2 += __shfl_xor(x2, off);
    }
    float ms = s1 * (1.f / 384.f), mx = x1 * (1.f / 384.f);
    float rs = rsqrtf(fmaxf(s2 * (1.f / 384.f) - ms * ms, 0.f) + 1e-5f);
    float rx = rsqrtf(fmaxf(x2 * (1.f / 384.f) - mx * mx, 0.f) + 1e-5f);
    int d = t / 784, rem = t % 784, hh = rem / 28, ww = rem % 28;
    int win = (d / 7) * 16 + (hh / 7) * 4 + (ww / 7);
    int n = (d % 7) * 49 + (hh % 7) * 7 + (ww % 7);
    size_t dst = ((size_t)(win * NTOK + n)) * C_DIM + lane;
    size_t td  = (size_t)t * C_DIM + lane;
#pragma unroll
    for (int j = 0; j < 6; j++) {
        int c = lane + j * 64;
        float gg = g[c], bb = bta[c];
        skW[dst + j * 64] = f2b((vs[j] - ms) * rs * gg + bb);
        qW[dst + j * 64]  = f2b((vx[j] - mx) * rx * gg + bb);
        res[td + j * 64]  = f2b(vs[j] + vx[j]);
    }
}

// ---------------------------------------------------------------------------
// Kernel 5: LayerNorm of x2 (bf16) -> lnx (bf16).
// ---------------------------------------------------------------------------
__global__ __launch_bounds__(256) void k_ln2(
    const u16* __restrict__ x2, const float* __restrict__ g,
    const float* __restrict__ bta, u16* __restrict__ lnx)
{
    int t = blockIdx.x * 4 + (threadIdx.x >> 6);
    int lane = threadIdx.x & 63;
    const u16* p = x2 + (size_t)t * C_DIM;
    float v[6];
    float s1 = 0.f, s2 = 0.f;
#pragma unroll
    for (int j = 0; j < 6; j++) {
        float a = u2f(p[lane + j * 64]);
        v[j] = a; s1 += a; s2 += a * a;
    }
#pragma unroll
    for (int off = 32; off; off >>= 1) {
        s1 += __shfl_xor(s1, off);
        s2 += __shfl_xor(s2, off);
    }
    float m = s1 * (1.f / 384.f);
    float r = rsqrtf(fmaxf(s2 * (1.f / 384.f) - m * m, 0.f) + 1e-5f);
    size_t dst = (size_t)t * C_DIM + lane;
#pragma unroll
    for (int j = 0; j < 6; j++) {
        int c = lane + j * 64;
        lnx[dst + j * 64] = f2b((v[j] - m) * r * g[c] + bta[c]);
    }
}

// ---------------------------------------------------------------------------
// 128x128 MFMA GEMM core: wave = 64 rows x 64 cols (2x2 wave grid).
// Per 32-K step per wave: 4 A + 4 B ds_read_b128, 16 MFMA.
// ---------------------------------------------------------------------------
#define BPAD 40   // LDS row stride in u16 (32 data + 8 pad; 2-way banks)

__device__ __forceinline__ void gemm128(
    const u16* __restrict__ A, const u16* __restrict__ Bt, int K, int M,
    int rowBase, int colBase, int tid,
    u16 (*As)[BPAD], u16 (*Bs)[BPAD], f32x4 acc[4][4])
{
    const int sr  = tid >> 2;
    const int scg = (tid & 3) << 3;
    const int lane = tid & 63, wv = tid >> 6;
    const int m16 = lane & 15, quad = lane >> 4;
    const int wr = (wv >> 1) << 6, wc = (wv & 1) << 6;

    int ra0 = min(rowBase + sr, M - 1);
    int ra1 = min(rowBase + 64 + sr, M - 1);
    const u16* pa0 = A + (size_t)ra0 * K + scg;
    const u16* pa1 = A + (size_t)ra1 * K + scg;
    const u16* pb0 = Bt + (size_t)(colBase + sr) * K + scg;
    const u16* pb1 = Bt + (size_t)(colBase + 64 + sr) * K + scg;

    uint4 a0 = *(const uint4*)pa0, a1 = *(const uint4*)pa1;
    uint4 b0 = *(const uint4*)pb0, b1 = *(const uint4*)pb1;

    for (int kk = 0; kk < K; kk += 32) {
        *(uint4*)&As[sr][scg]      = a0;
        *(uint4*)&As[64 + sr][scg] = a1;
        *(uint4*)&Bs[sr][scg]      = b0;
        *(uint4*)&Bs[64 + sr][scg] = b1;
        __syncthreads();
        if (kk + 32 < K) {
            a0 = *(const uint4*)(pa0 + kk + 32);
            a1 = *(const uint4*)(pa1 + kk + 32);
            b0 = *(const uint4*)(pb0 + kk + 32);
            b1 = *(const uint4*)(pb1 + kk + 32);
        }
        s16x8 af[4], bf[4];
#pragma unroll
        for (int rt = 0; rt < 4; rt++)
            af[rt] = *(const s16x8*)&As[wr + rt * 16 + m16][quad * 8];
#pragma unroll
        for (int bt = 0; bt < 4; bt++)
            bf[bt] = *(const s16x8*)&Bs[wc + bt * 16 + m16][quad * 8];
#pragma unroll
        for (int rt = 0; rt < 4; rt++)
#pragma unroll
        for (int bt = 0; bt < 4; bt++)
            acc[rt][bt] = __builtin_amdgcn_mfma_f32_16x16x32_bf16(af[rt], bf[bt], acc[rt][bt], 0, 0, 0);
        __syncthreads();
    }
}

// ---------------------------------------------------------------------------
// 64x128 MFMA GEMM core, double-buffered LDS, ONE barrier per 32-K phase,
// wave = 64 rows x 32 cols. Two named register sets; each load issued
// 2 phases before its LDS write. K % 64 == 0 required.
// ---------------------------------------------------------------------------
__device__ __forceinline__ void gemm64_db(
    const u16* __restrict__ A, const u16* __restrict__ Bt, int K, int M,
    int rowBase, int colBase, int tid,
    u16 (*As)[BPAD], u16 (*Bs)[BPAD], f32x4 acc[4][2])
{
    const int sr  = tid >> 2;          // 0..63 staging row
    const int scg = (tid & 3) << 3;    // u16 col offset {0,8,16,24}
    const int lane = tid & 63, wv = tid >> 6;
    const int m16 = lane & 15, quad = lane >> 4;
    const int wc = wv << 5;            // wave's 32-col slice

    int ra = min(rowBase + sr, M - 1);
    const u16* pa  = A + (size_t)ra * K + scg;
    const u16* pb0 = Bt + (size_t)(colBase + sr) * K + scg;
    const u16* pb1 = Bt + (size_t)(colBase + 64 + sr) * K + scg;

    uint4 aA = *(const uint4*)pa,        bA0 = *(const uint4*)pb0,        bA1 = *(const uint4*)pb1;
    uint4 aB = *(const uint4*)(pa + 32), bB0 = *(const uint4*)(pb0 + 32), bB1 = *(const uint4*)(pb1 + 32);

    // prologue: stage tile 0 into buf0, refill set A with tile 64
    *(uint4*)&As[sr][scg]      = aA;
    *(uint4*)&Bs[sr][scg]      = bA0;
    *(uint4*)&Bs[64 + sr][scg] = bA1;
    if (64 < K) {
        aA  = *(const uint4*)(pa + 64);
        bA0 = *(const uint4*)(pb0 + 64);
        bA1 = *(const uint4*)(pb1 + 64);
    }
    __syncthreads();

    for (int kk = 0; kk < K; kk += 64) {
        // ---- phase A: compute tile kk (buf0); stage tile kk+32 -> buf1 ----
        *(uint4*)&As[64 + sr][scg]  = aB;
        *(uint4*)&Bs[128 + sr][scg] = bB0;
        *(uint4*)&Bs[192 + sr][scg] = bB1;
        if (kk + 96 < K) {
            aB  = *(const uint4*)(pa  + kk + 96);
            bB0 = *(const uint4*)(pb0 + kk + 96);
            bB1 = *(const uint4*)(pb1 + kk + 96);
        }
        {
            s16x8 af[4], bf[2];
#pragma unroll
            for (int rt = 0; rt < 4; rt++)
                af[rt] = *(const s16x8*)&As[rt * 16 + m16][quad * 8];
#pragma unroll
            for (int bt = 0; bt < 2; bt++)
                bf[bt] = *(const s16x8*)&Bs[wc + bt * 16 + m16][quad * 8];
#pragma unroll
            for (int rt = 0; rt < 4; rt++)
#pragma unroll
            for (int bt = 0; bt < 2; bt++)
                acc[rt][bt] = __builtin_amdgcn_mfma_f32_16x16x32_bf16(af[rt], bf[bt], acc[rt][bt], 0, 0, 0);
        }
        __syncthreads();
        // ---- phase B: compute tile kk+32 (buf1); stage tile kk+64 -> buf0 ----
        if (kk + 64 < K) {
            *(uint4*)&As[sr][scg]      = aA;
            *(uint4*)&Bs[sr][scg]      = bA0;
            *(uint4*)&Bs[64 + sr][scg] = bA1;
        }
        if (kk + 128 < K) {
            aA  = *(const uint4*)(pa  + kk + 128);
            bA0 = *(const uint4*)(pb0 + kk + 128);
            bA1 = *(const uint4*)(pb1 + kk + 128);
        }
        {
            s16x8 af[4], bf[2];
#pragma unroll
            for (int rt = 0; rt < 4; rt++)
                af[rt] = *(const s16x8*)&As[64 + rt * 16 + m16][quad * 8];
#pragma unroll
            for (int bt = 0; bt < 2; bt++)
                bf[bt] = *(const s16x8*)&Bs[128 + wc + bt * 16 + m16][quad * 8];
#pragma unroll
            for (int rt = 0; rt < 4; rt++)
#pragma unroll
            for (int bt = 0; bt < 2; bt++)
                acc[rt][bt] = __builtin_amdgcn_mfma_f32_16x16x32_bf16(af[rt], bf[bt], acc[rt][bt], 0, 0, 0);
        }
        __syncthreads();
    }
}

#define EPI_SETUP \
    int lane = tid & 63, wv = tid >> 6, quad = lane >> 4, n16 = lane & 15;

// KV projection (K=384, N=768): scatter to K/V (w,head,n,d) bf16.
__global__ __launch_bounds__(256) void k_gemm_kv(
    const u16* __restrict__ A, const u16* __restrict__ Wt, const float* __restrict__ bias,
    u16* __restrict__ Kb, u16* __restrict__ Vb)
{
    __shared__ __align__(16) u16 As[128][BPAD];
    __shared__ __align__(16) u16 Bs[128][BPAD];
    f32x4 acc[4][4] = {};
    int tid = threadIdx.x;
    int rowBase = blockIdx.x * 128, colBase = blockIdx.y * 128;
    gemm128(A, Wt, 384, LTOT, rowBase, colBase, tid, As, Bs, acc);
    EPI_SETUP
    int wr = (wv >> 1) << 6, wc = (wv & 1) << 6;
#pragma unroll
    for (int bt = 0; bt < 4; bt++) {
        int col = colBase + wc + bt * 16 + n16;
        float bcol = bias[col];
        int isv = col >= 384;
        int remc = col - (isv ? 384 : 0);
        int hh = remc >> 5, dd = remc & 31;
#pragma unroll
        for (int rt = 0; rt < 4; rt++)
#pragma unroll
        for (int reg = 0; reg < 4; reg++) {
            int r = rowBase + wr + rt * 16 + quad * 4 + reg;
            if (r < LTOT) {
                int w = r / NTOK, nn = r % NTOK;
                size_t dst = ((size_t)((w * NHEAD + hh) * NTOK + nn)) * HD + dd;
                (isv ? Vb : Kb)[dst] = f2b(acc[rt][bt][reg] + bcol);
            }
        }
    }
}

// Output projection (K=384, N=384) + bias + residual res (bf16) -> x2 bf16.
__global__ __launch_bounds__(256) void k_gemm_proj(
    const u16* __restrict__ A, const u16* __restrict__ Wt, const float* __restrict__ bias,
    const u16* __restrict__ res, u16* __restrict__ x2)
{
    __shared__ __align__(16) u16 As[128][BPAD];   // 2 bufs x 64 rows
    __shared__ __align__(16) u16 Bs[256][BPAD];   // 2 bufs x 128 rows
    f32x4 acc[4][2] = {};
    int tid = threadIdx.x;
    int rowBase = blockIdx.x * 64, colBase = blockIdx.y * 128;
    gemm64_db(A, Wt, 384, LTOT, rowBase, colBase, tid, As, Bs, acc);
    EPI_SETUP
    int wc = wv << 5;
#pragma unroll
    for (int bt = 0; bt < 2; bt++) {
        int col = colBase + wc + bt * 16 + n16;
        float bcol = bias[col];
#pragma unroll
        for (int rt = 0; rt < 4; rt++)
#pragma unroll
        for (int reg = 0; reg < 4; reg++) {
            int r = rowBase + rt * 16 + quad * 4 + reg;
            if (r < LTOT) {
                size_t idx = (size_t)r * C_DIM + col;
                x2[idx] = f2b(acc[rt][bt][reg] + bcol + u2f(res[idx]));
            }
        }
    }
}

// MLP1 (K=384, N=1536) + bias + gelu -> h1 chunk bf16, pair-packed columns:
// within each 128-col block, cols (32p+n, 32p+16+n) -> packed u32 at 32p+2n.
// w2t is permuted identically (k_wt_pi) so mlp2 is unchanged.
__global__ __launch_bounds__(256) void k_gemm_mlp1(
    const u16* __restrict__ A, const u16* __restrict__ Wt, const float* __restrict__ bias,
    u16* __restrict__ h1c, int rowOfs)
{
    __shared__ __align__(16) u16 As[128][BPAD];
    __shared__ __align__(16) u16 Bs[128][BPAD];
    f32x4 acc[4][4] = {};
    int tid = threadIdx.x;
    int rowBase = rowOfs + blockIdx.x * 128, colBase = blockIdx.y * 128;
    gemm128(A, Wt, 384, LTOT, rowBase, colBase, tid, As, Bs, acc);
    EPI_SETUP
    int wr = (wv >> 1) << 6;
#pragma unroll
    for (int p2 = 0; p2 < 2; p2++) {
        int p = (wv & 1) * 2 + p2;            // global pair index 0..3
        int col0 = colBase + p * 32 + n16;    // ct = 2p
        int col1 = col0 + 16;                 // ct = 2p+1
        float bc0 = bias[col0], bc1 = bias[col1];
        int dcol = colBase + p * 32 + 2 * n16;
#pragma unroll
        for (int rt = 0; rt < 4; rt++)
#pragma unroll
        for (int reg = 0; reg < 4; reg++) {
            int r = rowBase + wr + rt * 16 + quad * 4 + reg;
            if (r < LTOT) {
                size_t rl = (size_t)(r - rowOfs);
                float v0 = gelu_fast(acc[rt][2 * p2][reg] + bc0);
                float v1 = gelu_fast(acc[rt][2 * p2 + 1][reg] + bc1);
                *(unsigned int*)&h1c[rl * 1536 + dcol] = pk_bf16(v0, v1);
            }
        }
    }
}

// MLP2 (K=1536 permuted, N=384) + bias + residual x2 (bf16) -> out f32 (final).
__global__ __launch_bounds__(256) void k_gemm_mlp2(
    const u16* __restrict__ A, const u16* __restrict__ Wt, const float* __restrict__ bias,
    const u16* __restrict__ x2, float* __restrict__ out, int rowOfs, int chunkRows)
{
    __shared__ __align__(16) u16 As[128][BPAD];   // 2 bufs x 64 rows
    __shared__ __align__(16) u16 Bs[256][BPAD];   // 2 bufs x 128 rows
    f32x4 acc[4][2] = {};
    int tid = threadIdx.x;
    int rowBase = blockIdx.x * 64, colBase = blockIdx.y * 128;   // local rows
    gemm64_db(A, Wt, 1536, chunkRows, rowBase, colBase, tid, As, Bs, acc);
    EPI_SETUP
    int wc = wv << 5;
#pragma unroll
    for (int bt = 0; bt < 2; bt++) {
        int col = colBase + wc + bt * 16 + n16;
        float bcol = bias[col];
#pragma unroll
        for (int rt = 0; rt < 4; rt++)
#pragma unroll
        for (int reg = 0; reg < 4; reg++) {
            int rl = rowBase + rt * 16 + quad * 4 + reg;
            int rg = rowOfs + rl;
            if (rl < chunkRows && rg < LTOT) {
                size_t idx = (size_t)rg * C_DIM + col;
                out[idx] = acc[rt][bt][reg] + bcol + u2f(x2[idx]);
            }
        }
    }
}

// ---------------------------------------------------------------------------
// Kernel 3: MFMA flash attention. One 256-thread block (4 waves) per
// (head, window). K is NOT staged in LDS: its MFMA fragment is contiguous
// in Kb's (n,d) layout, and each block's 22 KB K-panel is L2-resident --
// staging it only halved occupancy. V stays in LDS (transposed+pair-packed
// fragment is a gather from global).
// LDS: Vt 23040 + rp16 4400 + code 704 + Pb 4608 = 32752 B -> 4 blocks/CU
// (16 waves/CU) with launch_bounds(256,4) capping VGPR at 128.
// All 768 blocks co-resident.
// ---------------------------------------------------------------------------
#define VP  360    // Vt row stride (u16), 720 B: 16B-aligned, 8-bank spread
#define PBS 36     // Pb row stride (u16), 72 B: 8B-aligned (read as 2xb64)

__global__ __launch_bounds__(256, 4) void k_attn(
    const u16* __restrict__ qW, const u16* __restrict__ Kb, const u16* __restrict__ Vb,
    const float* __restrict__ rpb, u16* __restrict__ oT)
{
    __shared__ __align__(16) u16 Vt[32 * VP];        // 23040 B
    __shared__ __align__(16) u16 rp16[2200];         //  4400 B
    __shared__ __align__(16) u16 code[352];          //   704 B
    __shared__ __align__(16) u16 Pb[4 * 16 * PBS];   //  4608 B

    const int h = blockIdx.x, w = blockIdx.y;
    const int tid = threadIdx.x;
    const int lane = tid & 63, wv = tid >> 6;
    const int m16 = lane & 15, quad = lane >> 4;
    const size_t base = ((size_t)(w * NHEAD + h)) * NTOK * HD;
    const u16* Kg = Kb + base;

    // V transposed [d][col], col = 32*kb + 2*j (token kb*32+j) | +1 (token +16).
    for (int t = tid; t < 704; t += 256) {
        int dg = t / 176, rem = t - dg * 176;
        int kb = rem >> 4, j = rem & 15;
        int n0 = kb * 32 + j, n1 = n0 + 16;
        uint4 uA = make_uint4(0, 0, 0, 0), uB = make_uint4(0, 0, 0, 0);
        if (n0 < NTOK) uA = *(const uint4*)(Vb + base + n0 * HD + dg * 8);
        if (n1 < NTOK) uB = *(const uint4*)(Vb + base + n1 * HD + dg * 8);
        int d0 = dg * 8, colu = kb * 32 + 2 * j;
        unsigned int pk0 = (uA.x & 0xffffu) | (uB.x << 16);
        unsigned int pk1 = (uA.x >> 16)     | (uB.x & 0xffff0000u);
        unsigned int pk2 = (uA.y & 0xffffu) | (uB.y << 16);
        unsigned int pk3 = (uA.y >> 16)     | (uB.y & 0xffff0000u);
        unsigned int pk4 = (uA.z & 0xffffu) | (uB.z << 16);
        unsigned int pk5 = (uA.z >> 16)     | (uB.z & 0xffff0000u);
        unsigned int pk6 = (uA.w & 0xffffu) | (uB.w << 16);
        unsigned int pk7 = (uA.w >> 16)     | (uB.w & 0xffff0000u);
        *(unsigned int*)&Vt[(d0 + 0) * VP + colu] = pk0;
        *(unsigned int*)&Vt[(d0 + 1) * VP + colu] = pk1;
        *(unsigned int*)&Vt[(d0 + 2) * VP + colu] = pk2;
        *(unsigned int*)&Vt[(d0 + 3) * VP + colu] = pk3;
        *(unsigned int*)&Vt[(d0 + 4) * VP + colu] = pk4;
        *(unsigned int*)&Vt[(d0 + 5) * VP + colu] = pk5;
        *(unsigned int*)&Vt[(d0 + 6) * VP + colu] = pk6;
        *(unsigned int*)&Vt[(d0 + 7) * VP + colu] = pk7;
    }
    // bias table in log2 units
    for (int t = tid; t < 2200; t += 256)
        rp16[t] = (t < 2197) ? f2b(rpb[t * NHEAD + h] * 1.4426950408889634f) : (u16)0;
    for (int t = tid; t < 352; t += 256) {
        int z = t / 49, rem = t % 49, y = rem / 7, x = rem % 7;
        code[t] = (t < NTOK) ? (u16)(z * 169 + y * 13 + x) : (u16)1098;
    }
    __syncthreads();

    const float scale = 0.2550348772f;  // (1/sqrt(32)) * log2(e)
    u16* myP = Pb + wv * 16 * PBS;

    for (int qt = wv; qt < 22; qt += 4) {
        int qbase = qt * 16;
        int qrow = min(qbase + m16, NTOK - 1);
        s16x8 qf = *(const s16x8*)(qW + ((size_t)(w * NTOK + qrow)) * C_DIM
                                       + h * HD + quad * 8);
        int qcv[4];
#pragma unroll
        for (int i = 0; i < 4; i++) qcv[i] = code[qbase + quad * 4 + i];

        f32x4 S0[11], S1[11];
        float mx[4] = {-1e30f, -1e30f, -1e30f, -1e30f};

#pragma unroll
        for (int ks = 0; ks < 11; ks++) {
            int kbase = ks * 32;
            int kt0 = kbase + m16, kt1 = kt0 + 16;
            // K fragments straight from global (L2-resident); kt1 rows past
            // NTOK read garbage within the workspace -- masked by k1ok below.
            s16x8 kf0 = *(const s16x8*)(Kg + (size_t)kt0 * HD + quad * 8);
            s16x8 kf1 = *(const s16x8*)(Kg + (size_t)kt1 * HD + quad * 8);
            f32x4 z = {0.f, 0.f, 0.f, 0.f};
            f32x4 sA = __builtin_amdgcn_mfma_f32_16x16x32_bf16(qf, kf0, z, 0, 0, 0);
            f32x4 sB = __builtin_amdgcn_mfma_f32_16x16x32_bf16(qf, kf1, z, 0, 0, 0);
            int kc0 = code[kt0], kc1 = code[kt1];
            bool k1ok = (ks < 10) || (kt1 < NTOK);
#pragma unroll
            for (int i = 0; i < 4; i++) {
                float b0 = u2f(rp16[qcv[i] - kc0 + 1098]);
                float b1 = u2f(rp16[qcv[i] - kc1 + 1098]);
                float sa = fmaf(sA[i], scale, b0);
                float sb = k1ok ? fmaf(sB[i], scale, b1) : -1e30f;
                S0[ks][i] = sa;
                S1[ks][i] = sb;
                mx[i] = fmaxf(mx[i], fmaxf(sa, sb));
            }
        }
#pragma unroll
        for (int i = 0; i < 4; i++) {
            float v = mx[i];
            v = fmaxf(v, __shfl_xor(v, 1));
            v = fmaxf(v, __shfl_xor(v, 2));
            v = fmaxf(v, __shfl_xor(v, 4));
            v = fmaxf(v, __shfl_xor(v, 8));
            mx[i] = v;
        }

        f32x4 O0 = {}, O1 = {};
        float l[4] = {};
#pragma unroll
        for (int ks = 0; ks < 11; ks++) {
            int kbase = ks * 32;
#pragma unroll
            for (int i = 0; i < 4; i++) {
                float pa = exp2_hw(S0[ks][i] - mx[i]);   // col 2*m16   (k=m16)
                float pb = exp2_hw(S1[ks][i] - mx[i]);   // col 2*m16+1 (k=16+m16)
                l[i] += pa + pb;
                *(unsigned int*)&myP[(quad * 4 + i) * PBS + 2 * m16] = pk_bf16(pa, pb);
            }
            s16x4 plo = *(const s16x4*)&myP[m16 * PBS + quad * 8];
            s16x4 phi = *(const s16x4*)&myP[m16 * PBS + quad * 8 + 4];
            s16x8 pf  = __builtin_shufflevector(plo, phi, 0, 1, 2, 3, 4, 5, 6, 7);
            s16x8 vf0 = *(const s16x8*)&Vt[m16 * VP + kbase + quad * 8];
            s16x8 vf1 = *(const s16x8*)&Vt[(16 + m16) * VP + kbase + quad * 8];
            O0 = __builtin_amdgcn_mfma_f32_16x16x32_bf16(pf, vf0, O0, 0, 0, 0);
            O1 = __builtin_amdgcn_mfma_f32_16x16x32_bf16(pf, vf1, O1, 0, 0, 0);
        }
#pragma unroll
        for (int i = 0; i < 4; i++) {
            float v = l[i];
            v += __shfl_xor(v, 1);
            v += __shfl_xor(v, 2);
            v += __shfl_xor(v, 4);
            v += __shfl_xor(v, 8);
            l[i] = v;
        }

        int wd = w >> 4, wh = (w >> 2) & 3, wwi = w & 3;
#pragma unroll
        for (int i = 0; i < 4; i++) {
            int q = qbase + quad * 4 + i;
            if (q < NTOK) {
                float rl = __builtin_amdgcn_rcpf(l[i]);
                int qz = q / 49, qrem = q % 49, qy = qrem / 7, qx = qrem % 7;
                size_t tok = ((size_t)(wd * 7 + qz) * SIDE + (wh * 7 + qy)) * SIDE
                             + (wwi * 7 + qx);
                u16* op = oT + tok * C_DIM + h * HD;
                op[m16]      = f2b(O0[i] * rl);
                op[16 + m16] = f2b(O1[i] * rl);
            }
        }
    }
}

// ---------------------------------------------------------------------------
// Workspace layout unchanged.
// ---------------------------------------------------------------------------
extern "C" void kernel_launch(void* const* d_in, const int* in_sizes, int n_in,
                              void* d_out, int out_size, void* d_ws, size_t ws_size,
                              hipStream_t stream)
{
    const float* skip = (const float*)d_in[0];
    const float* xup  = (const float*)d_in[1];
    const float* ln1g = (const float*)d_in[5];
    const float* ln1b = (const float*)d_in[6];
    const float* kvw  = (const float*)d_in[7];
    const float* kvb  = (const float*)d_in[8];
    const float* rpb  = (const float*)d_in[9];
    const float* pw   = (const float*)d_in[10];
    const float* pb   = (const float*)d_in[11];
    const float* ln2g = (const float*)d_in[12];
    const float* ln2b = (const float*)d_in[13];
    const float* w1   = (const float*)d_in[14];
    const float* b1   = (const float*)d_in[15];
    const float* w2   = (const float*)d_in[16];
    const float* b2   = (const float*)d_in[17];
    float* out = (float*)d_out;

    char* ws = (char*)d_ws;
    const size_t BUFB = (size_t)LTOT * C_DIM * 2;   // 16,859,136 B
    const size_t WTB  = 589824 + 294912 + 1179648 + 1179648;  // 3,244,032 B
    u16* skW = (u16*)(ws);
    u16* qW  = (u16*)(ws + BUFB);
    u16* Kb  = (u16*)(ws + 2 * BUFB);
    u16* Vb  = (u16*)(ws + 3 * BUFB);
    u16* oT  = (u16*)(ws);                  // overlays skW (dead)
    u16* x2  = (u16*)(ws + BUFB);           // overlays qW (dead)
    u16* lnx = (u16*)(ws + 2 * BUFB);       // overlays Kb (dead)
    char* wt = ws + 4 * BUFB;
    u16* kvWt = (u16*)(wt);
    u16* pWt  = (u16*)(wt + 589824);
    u16* w1t  = (u16*)(wt + 589824 + 294912);
    u16* w2t  = (u16*)(wt + 589824 + 294912 + 1179648);
    u16* res  = (u16*)d_out;                // scratch in d_out (dead until mlp2)

    const size_t used = 4 * BUFB + WTB;
    const size_t blkBytes = 128 * 1536 * 2;         // 393,216 B
    size_t tailCap = (ws_size > used) ? (ws_size - used) / blkBytes : 0;
    int chunkBlocks;
    u16* h1c;
    if (tailCap >= 43) {
        chunkBlocks = tailCap < 172 ? (int)tailCap : 172;
        h1c = (u16*)(ws + used);
    } else {
        chunkBlocks = 42;                            // fits in s3 (Vb, dead)
        h1c = (u16*)(ws + 3 * BUFB);
    }

    k_wt<<<dim3(6, 12), 256, 0, stream>>>(kvw, kvWt, 384, 768);
    k_wt<<<dim3(6, 6),  256, 0, stream>>>(pw,  pWt,  384, 384);
    k_wt<<<dim3(6, 24), 256, 0, stream>>>(w1,  w1t,  384, 1536);
    k_wt_pi<<<dim3(24, 6), 256, 0, stream>>>(w2, w2t, 1536, 384);

    k_lnprep<<<LTOT / 4, 256, 0, stream>>>(skip, xup, ln1g, ln1b, skW, qW, res);
    k_gemm_kv<<<dim3(172, 6), 256, 0, stream>>>(skW, kvWt, kvb, Kb, Vb);
    k_attn<<<dim3(NHEAD, NWIN), 256, 0, stream>>>(qW, Kb, Vb, rpb, oT);
    k_gemm_proj<<<dim3(343, 3), 256, 0, stream>>>(oT, pWt, pb, res, x2);
    k_ln2<<<LTOT / 4, 256, 0, stream>>>(x2, ln2g, ln2b, lnx);
    for (int b0 = 0; b0 < 172; b0 += chunkBlocks) {
        int nb = (172 - b0) < chunkBlocks ? (172 - b0) : chunkBlocks;
        int rowOfs = b0 * 128;
        int chunkRows = nb * 128;
        if (rowOfs + chunkRows > LTOT) chunkRows = LTOT - rowOfs;
        int nb64 = (chunkRows + 63) / 64;
        k_gemm_mlp1<<<dim3(nb, 12), 256, 0, stream>>>(lnx, w1t, b1, h1c, rowOfs);
        k_gemm_mlp2<<<dim3(nb64, 3), 256, 0, stream>>>(h1c, w2t, b2, x2, out, rowOfs, chunkRows);
    }
}

// Round 7
// 436.883 us; speedup vs baseline: 1.0956x; 1.0956x over previous
//
#include <hip/hip_runtime.h>
#include <hip/hip_bf16.h>
#include <cstdint>

typedef unsigned short u16;
typedef short s16x8 __attribute__((ext_vector_type(8)));
typedef short s16x4 __attribute__((ext_vector_type(4)));
typedef float f32x4 __attribute__((ext_vector_type(4)));

#define C_DIM 384
#define NHEAD 12
#define HD    32
#define NTOK  343     // tokens per window (7^3)
#define NWIN  64
#define LTOT  21952   // 28^3
#define SIDE  28

__device__ __forceinline__ float u2f(u16 u) {
    return __uint_as_float(((unsigned int)u) << 16);
}
__device__ __forceinline__ u16 f2b(float f) {
    unsigned int u = __float_as_uint(f);
    return (u16)((u + 0x7fffu + ((u >> 16) & 1u)) >> 16);   // RNE
}
__device__ __forceinline__ float exp2_hw(float x) {
    float r;
    asm("v_exp_f32 %0, %1" : "=v"(r) : "v"(x));
    return r;
}
// pack two f32 -> two bf16 (RNE) in one op
__device__ __forceinline__ unsigned int pk_bf16(float lo, float hi) {
    unsigned int r;
    asm("v_cvt_pk_bf16_f32 %0, %1, %2" : "=v"(r) : "v"(lo), "v"(hi));
    return r;
}
// gelu tanh-approx: 0.5x(1+tanh(z)) == x / (1 + 2^(-2z*log2e))
__device__ __forceinline__ float gelu_fast(float x) {
    float e = exp2_hw(-2.3022083f * (x + 0.044715f * x * x * x));
    return x * __builtin_amdgcn_rcpf(1.f + e);
}

// ---------------------------------------------------------------------------
// Weight transpose + f32->bf16: Wt[n][k] = bf16(W[k][n]).  W is KxN row-major.
// ---------------------------------------------------------------------------
__global__ __launch_bounds__(256) void k_wt(
    const float* __restrict__ W, u16* __restrict__ Wt, int K, int N)
{
    __shared__ float T[64][65];
    int k0 = blockIdx.x * 64, n0 = blockIdx.y * 64;
    int t = threadIdx.x;
    int c = t & 63, rg = t >> 6;
#pragma unroll
    for (int i = 0; i < 16; i++) {
        int r = rg * 16 + i;
        T[r][c] = W[(size_t)(k0 + r) * N + n0 + c];
    }
    __syncthreads();
    int k = t & 63, ng = t >> 6;
#pragma unroll
    for (int i = 0; i < 16; i++) {
        int n = ng * 16 + i;
        Wt[(size_t)(n0 + n) * K + k0 + k] = f2b(T[k][n]);
    }
}

// Same, but the k (contraction) index is pi-permuted within each 128-block:
// j = k%128 = ct*16+n  ->  j' = 32*(ct>>1) + 2*n + (ct&1).
// Used for w2 so mlp1 can store h1 in pair-packed column order.
__global__ __launch_bounds__(256) void k_wt_pi(
    const float* __restrict__ W, u16* __restrict__ Wt, int K, int N)
{
    __shared__ float T[64][65];
    int k0 = blockIdx.x * 64, n0 = blockIdx.y * 64;
    int t = threadIdx.x;
    int c = t & 63, rg = t >> 6;
#pragma unroll
    for (int i = 0; i < 16; i++) {
        int r = rg * 16 + i;
        T[r][c] = W[(size_t)(k0 + r) * N + n0 + c];
    }
    __syncthreads();
    int k = t & 63, ng = t >> 6;
    int kg = k0 + k;
    int j = kg & 127, ct = j >> 4, nn = j & 15;
    int kp = (kg & ~127) | ((ct >> 1) << 5) | (nn << 1) | (ct & 1);
#pragma unroll
    for (int i = 0; i < 16; i++) {
        int n = ng * 16 + i;
        Wt[(size_t)(n0 + n) * K + kp] = f2b(T[k][n]);
    }
}

// ---------------------------------------------------------------------------
// Kernel 1: dual LayerNorm + window partition -> bf16; also res = bf16(skip+xup)
// ---------------------------------------------------------------------------
__global__ __launch_bounds__(256) void k_lnprep(
    const float* __restrict__ skip, const float* __restrict__ xup,
    const float* __restrict__ g, const float* __restrict__ bta,
    u16* __restrict__ skW, u16* __restrict__ qW, u16* __restrict__ res)
{
    int t = blockIdx.x * 4 + (threadIdx.x >> 6);
    int lane = threadIdx.x & 63;
    const float* ps = skip + (size_t)t * C_DIM;
    const float* px = xup + (size_t)t * C_DIM;
    float vs[6], vx[6];
    float s1 = 0.f, s2 = 0.f, x1 = 0.f, x2 = 0.f;
#pragma unroll
    for (int j = 0; j < 6; j++) {
        float a = ps[lane + j * 64];
        float b = px[lane + j * 64];
        vs[j] = a; vx[j] = b;
        s1 += a; s2 += a * a; x1 += b; x2 += b * b;
    }
#pragma unroll
    for (int off = 32; off; off >>= 1) {
        s1 += __shfl_xor(s1, off);
        s2 += __shfl_xor(s2, off);
        x1 += __shfl_xor(x1, off);
        x2 += __shfl_xor(x2, off);
    }
    float ms = s1 * (1.f / 384.f), mx = x1 * (1.f / 384.f);
    float rs = rsqrtf(fmaxf(s2 * (1.f / 384.f) - ms * ms, 0.f) + 1e-5f);
    float rx = rsqrtf(fmaxf(x2 * (1.f / 384.f) - mx * mx, 0.f) + 1e-5f);
    int d = t / 784, rem = t % 784, hh = rem / 28, ww = rem % 28;
    int win = (d / 7) * 16 + (hh / 7) * 4 + (ww / 7);
    int n = (d % 7) * 49 + (hh % 7) * 7 + (ww % 7);
    size_t dst = ((size_t)(win * NTOK + n)) * C_DIM + lane;
    size_t td  = (size_t)t * C_DIM + lane;
#pragma unroll
    for (int j = 0; j < 6; j++) {
        int c = lane + j * 64;
        float gg = g[c], bb = bta[c];
        skW[dst + j * 64] = f2b((vs[j] - ms) * rs * gg + bb);
        qW[dst + j * 64]  = f2b((vx[j] - mx) * rx * gg + bb);
        res[td + j * 64]  = f2b(vs[j] + vx[j]);
    }
}

// ---------------------------------------------------------------------------
// Kernel 5: LayerNorm of x2 (bf16) -> lnx (bf16).
// ---------------------------------------------------------------------------
__global__ __launch_bounds__(256) void k_ln2(
    const u16* __restrict__ x2, const float* __restrict__ g,
    const float* __restrict__ bta, u16* __restrict__ lnx)
{
    int t = blockIdx.x * 4 + (threadIdx.x >> 6);
    int lane = threadIdx.x & 63;
    const u16* p = x2 + (size_t)t * C_DIM;
    float v[6];
    float s1 = 0.f, s2 = 0.f;
#pragma unroll
    for (int j = 0; j < 6; j++) {
        float a = u2f(p[lane + j * 64]);
        v[j] = a; s1 += a; s2 += a * a;
    }
#pragma unroll
    for (int off = 32; off; off >>= 1) {
        s1 += __shfl_xor(s1, off);
        s2 += __shfl_xor(s2, off);
    }
    float m = s1 * (1.f / 384.f);
    float r = rsqrtf(fmaxf(s2 * (1.f / 384.f) - m * m, 0.f) + 1e-5f);
    size_t dst = (size_t)t * C_DIM + lane;
#pragma unroll
    for (int j = 0; j < 6; j++) {
        int c = lane + j * 64;
        lnx[dst + j * 64] = f2b((v[j] - m) * r * g[c] + bta[c]);
    }
}

// ---------------------------------------------------------------------------
// 128x128 MFMA GEMM core: wave = 64 rows x 64 cols (2x2 wave grid).
// Per 32-K step per wave: 4 A + 4 B ds_read_b128, 16 MFMA.
// ---------------------------------------------------------------------------
#define BPAD 40   // LDS row stride in u16 (32 data + 8 pad; 2-way banks)

__device__ __forceinline__ void gemm128(
    const u16* __restrict__ A, const u16* __restrict__ Bt, int K, int M,
    int rowBase, int colBase, int tid,
    u16 (*As)[BPAD], u16 (*Bs)[BPAD], f32x4 acc[4][4])
{
    const int sr  = tid >> 2;
    const int scg = (tid & 3) << 3;
    const int lane = tid & 63, wv = tid >> 6;
    const int m16 = lane & 15, quad = lane >> 4;
    const int wr = (wv >> 1) << 6, wc = (wv & 1) << 6;

    int ra0 = min(rowBase + sr, M - 1);
    int ra1 = min(rowBase + 64 + sr, M - 1);
    const u16* pa0 = A + (size_t)ra0 * K + scg;
    const u16* pa1 = A + (size_t)ra1 * K + scg;
    const u16* pb0 = Bt + (size_t)(colBase + sr) * K + scg;
    const u16* pb1 = Bt + (size_t)(colBase + 64 + sr) * K + scg;

    uint4 a0 = *(const uint4*)pa0, a1 = *(const uint4*)pa1;
    uint4 b0 = *(const uint4*)pb0, b1 = *(const uint4*)pb1;

    for (int kk = 0; kk < K; kk += 32) {
        *(uint4*)&As[sr][scg]      = a0;
        *(uint4*)&As[64 + sr][scg] = a1;
        *(uint4*)&Bs[sr][scg]      = b0;
        *(uint4*)&Bs[64 + sr][scg] = b1;
        __syncthreads();
        if (kk + 32 < K) {
            a0 = *(const uint4*)(pa0 + kk + 32);
            a1 = *(const uint4*)(pa1 + kk + 32);
            b0 = *(const uint4*)(pb0 + kk + 32);
            b1 = *(const uint4*)(pb1 + kk + 32);
        }
        s16x8 af[4], bf[4];
#pragma unroll
        for (int rt = 0; rt < 4; rt++)
            af[rt] = *(const s16x8*)&As[wr + rt * 16 + m16][quad * 8];
#pragma unroll
        for (int bt = 0; bt < 4; bt++)
            bf[bt] = *(const s16x8*)&Bs[wc + bt * 16 + m16][quad * 8];
#pragma unroll
        for (int rt = 0; rt < 4; rt++)
#pragma unroll
        for (int bt = 0; bt < 4; bt++)
            acc[rt][bt] = __builtin_amdgcn_mfma_f32_16x16x32_bf16(af[rt], bf[bt], acc[rt][bt], 0, 0, 0);
        __syncthreads();
    }
}

// ---------------------------------------------------------------------------
// 64x128 MFMA GEMM core, double-buffered LDS, ONE barrier per 32-K phase,
// wave = 64 rows x 32 cols. Two named register sets; each load issued
// 2 phases before its LDS write. K % 64 == 0 required.
// ---------------------------------------------------------------------------
__device__ __forceinline__ void gemm64_db(
    const u16* __restrict__ A, const u16* __restrict__ Bt, int K, int M,
    int rowBase, int colBase, int tid,
    u16 (*As)[BPAD], u16 (*Bs)[BPAD], f32x4 acc[4][2])
{
    const int sr  = tid >> 2;          // 0..63 staging row
    const int scg = (tid & 3) << 3;    // u16 col offset {0,8,16,24}
    const int lane = tid & 63, wv = tid >> 6;
    const int m16 = lane & 15, quad = lane >> 4;
    const int wc = wv << 5;            // wave's 32-col slice

    int ra = min(rowBase + sr, M - 1);
    const u16* pa  = A + (size_t)ra * K + scg;
    const u16* pb0 = Bt + (size_t)(colBase + sr) * K + scg;
    const u16* pb1 = Bt + (size_t)(colBase + 64 + sr) * K + scg;

    uint4 aA = *(const uint4*)pa,        bA0 = *(const uint4*)pb0,        bA1 = *(const uint4*)pb1;
    uint4 aB = *(const uint4*)(pa + 32), bB0 = *(const uint4*)(pb0 + 32), bB1 = *(const uint4*)(pb1 + 32);

    // prologue: stage tile 0 into buf0, refill set A with tile 64
    *(uint4*)&As[sr][scg]      = aA;
    *(uint4*)&Bs[sr][scg]      = bA0;
    *(uint4*)&Bs[64 + sr][scg] = bA1;
    if (64 < K) {
        aA  = *(const uint4*)(pa + 64);
        bA0 = *(const uint4*)(pb0 + 64);
        bA1 = *(const uint4*)(pb1 + 64);
    }
    __syncthreads();

    for (int kk = 0; kk < K; kk += 64) {
        // ---- phase A: compute tile kk (buf0); stage tile kk+32 -> buf1 ----
        *(uint4*)&As[64 + sr][scg]  = aB;
        *(uint4*)&Bs[128 + sr][scg] = bB0;
        *(uint4*)&Bs[192 + sr][scg] = bB1;
        if (kk + 96 < K) {
            aB  = *(const uint4*)(pa  + kk + 96);
            bB0 = *(const uint4*)(pb0 + kk + 96);
            bB1 = *(const uint4*)(pb1 + kk + 96);
        }
        {
            s16x8 af[4], bf[2];
#pragma unroll
            for (int rt = 0; rt < 4; rt++)
                af[rt] = *(const s16x8*)&As[rt * 16 + m16][quad * 8];
#pragma unroll
            for (int bt = 0; bt < 2; bt++)
                bf[bt] = *(const s16x8*)&Bs[wc + bt * 16 + m16][quad * 8];
#pragma unroll
            for (int rt = 0; rt < 4; rt++)
#pragma unroll
            for (int bt = 0; bt < 2; bt++)
                acc[rt][bt] = __builtin_amdgcn_mfma_f32_16x16x32_bf16(af[rt], bf[bt], acc[rt][bt], 0, 0, 0);
        }
        __syncthreads();
        // ---- phase B: compute tile kk+32 (buf1); stage tile kk+64 -> buf0 ----
        if (kk + 64 < K) {
            *(uint4*)&As[sr][scg]      = aA;
            *(uint4*)&Bs[sr][scg]      = bA0;
            *(uint4*)&Bs[64 + sr][scg] = bA1;
        }
        if (kk + 128 < K) {
            aA  = *(const uint4*)(pa  + kk + 128);
            bA0 = *(const uint4*)(pb0 + kk + 128);
            bA1 = *(const uint4*)(pb1 + kk + 128);
        }
        {
            s16x8 af[4], bf[2];
#pragma unroll
            for (int rt = 0; rt < 4; rt++)
                af[rt] = *(const s16x8*)&As[64 + rt * 16 + m16][quad * 8];
#pragma unroll
            for (int bt = 0; bt < 2; bt++)
                bf[bt] = *(const s16x8*)&Bs[128 + wc + bt * 16 + m16][quad * 8];
#pragma unroll
            for (int rt = 0; rt < 4; rt++)
#pragma unroll
            for (int bt = 0; bt < 2; bt++)
                acc[rt][bt] = __builtin_amdgcn_mfma_f32_16x16x32_bf16(af[rt], bf[bt], acc[rt][bt], 0, 0, 0);
        }
        __syncthreads();
    }
}

#define EPI_SETUP \
    int lane = tid & 63, wv = tid >> 6, quad = lane >> 4, n16 = lane & 15;

// KV projection (K=384, N=768): scatter to K/V (w,head,n,d) bf16.
__global__ __launch_bounds__(256) void k_gemm_kv(
    const u16* __restrict__ A, const u16* __restrict__ Wt, const float* __restrict__ bias,
    u16* __restrict__ Kb, u16* __restrict__ Vb)
{
    __shared__ __align__(16) u16 As[128][BPAD];
    __shared__ __align__(16) u16 Bs[128][BPAD];
    f32x4 acc[4][4] = {};
    int tid = threadIdx.x;
    int rowBase = blockIdx.x * 128, colBase = blockIdx.y * 128;
    gemm128(A, Wt, 384, LTOT, rowBase, colBase, tid, As, Bs, acc);
    EPI_SETUP
    int wr = (wv >> 1) << 6, wc = (wv & 1) << 6;
#pragma unroll
    for (int bt = 0; bt < 4; bt++) {
        int col = colBase + wc + bt * 16 + n16;
        float bcol = bias[col];
        int isv = col >= 384;
        int remc = col - (isv ? 384 : 0);
        int hh = remc >> 5, dd = remc & 31;
#pragma unroll
        for (int rt = 0; rt < 4; rt++)
#pragma unroll
        for (int reg = 0; reg < 4; reg++) {
            int r = rowBase + wr + rt * 16 + quad * 4 + reg;
            if (r < LTOT) {
                int w = r / NTOK, nn = r % NTOK;
                size_t dst = ((size_t)((w * NHEAD + hh) * NTOK + nn)) * HD + dd;
                (isv ? Vb : Kb)[dst] = f2b(acc[rt][bt][reg] + bcol);
            }
        }
    }
}

// Output projection (K=384, N=384) + bias + residual res (bf16) -> x2 bf16.
__global__ __launch_bounds__(256) void k_gemm_proj(
    const u16* __restrict__ A, const u16* __restrict__ Wt, const float* __restrict__ bias,
    const u16* __restrict__ res, u16* __restrict__ x2)
{
    __shared__ __align__(16) u16 As[128][BPAD];   // 2 bufs x 64 rows
    __shared__ __align__(16) u16 Bs[256][BPAD];   // 2 bufs x 128 rows
    f32x4 acc[4][2] = {};
    int tid = threadIdx.x;
    int rowBase = blockIdx.x * 64, colBase = blockIdx.y * 128;
    gemm64_db(A, Wt, 384, LTOT, rowBase, colBase, tid, As, Bs, acc);
    EPI_SETUP
    int wc = wv << 5;
#pragma unroll
    for (int bt = 0; bt < 2; bt++) {
        int col = colBase + wc + bt * 16 + n16;
        float bcol = bias[col];
#pragma unroll
        for (int rt = 0; rt < 4; rt++)
#pragma unroll
        for (int reg = 0; reg < 4; reg++) {
            int r = rowBase + rt * 16 + quad * 4 + reg;
            if (r < LTOT) {
                size_t idx = (size_t)r * C_DIM + col;
                x2[idx] = f2b(acc[rt][bt][reg] + bcol + u2f(res[idx]));
            }
        }
    }
}

// MLP1 (K=384, N=1536) + bias + gelu -> h1 chunk bf16, pair-packed columns:
// within each 128-col block, cols (32p+n, 32p+16+n) -> packed u32 at 32p+2n.
// w2t is permuted identically (k_wt_pi) so mlp2 is unchanged.
__global__ __launch_bounds__(256) void k_gemm_mlp1(
    const u16* __restrict__ A, const u16* __restrict__ Wt, const float* __restrict__ bias,
    u16* __restrict__ h1c, int rowOfs)
{
    __shared__ __align__(16) u16 As[128][BPAD];
    __shared__ __align__(16) u16 Bs[128][BPAD];
    f32x4 acc[4][4] = {};
    int tid = threadIdx.x;
    int rowBase = rowOfs + blockIdx.x * 128, colBase = blockIdx.y * 128;
    gemm128(A, Wt, 384, LTOT, rowBase, colBase, tid, As, Bs, acc);
    EPI_SETUP
    int wr = (wv >> 1) << 6;
#pragma unroll
    for (int p2 = 0; p2 < 2; p2++) {
        int p = (wv & 1) * 2 + p2;            // global pair index 0..3
        int col0 = colBase + p * 32 + n16;    // ct = 2p
        int col1 = col0 + 16;                 // ct = 2p+1
        float bc0 = bias[col0], bc1 = bias[col1];
        int dcol = colBase + p * 32 + 2 * n16;
#pragma unroll
        for (int rt = 0; rt < 4; rt++)
#pragma unroll
        for (int reg = 0; reg < 4; reg++) {
            int r = rowBase + wr + rt * 16 + quad * 4 + reg;
            if (r < LTOT) {
                size_t rl = (size_t)(r - rowOfs);
                float v0 = gelu_fast(acc[rt][2 * p2][reg] + bc0);
                float v1 = gelu_fast(acc[rt][2 * p2 + 1][reg] + bc1);
                *(unsigned int*)&h1c[rl * 1536 + dcol] = pk_bf16(v0, v1);
            }
        }
    }
}

// MLP2 (K=1536 permuted, N=384) + bias + residual x2 (bf16) -> out f32 (final).
__global__ __launch_bounds__(256) void k_gemm_mlp2(
    const u16* __restrict__ A, const u16* __restrict__ Wt, const float* __restrict__ bias,
    const u16* __restrict__ x2, float* __restrict__ out, int rowOfs, int chunkRows)
{
    __shared__ __align__(16) u16 As[128][BPAD];   // 2 bufs x 64 rows
    __shared__ __align__(16) u16 Bs[256][BPAD];   // 2 bufs x 128 rows
    f32x4 acc[4][2] = {};
    int tid = threadIdx.x;
    int rowBase = blockIdx.x * 64, colBase = blockIdx.y * 128;   // local rows
    gemm64_db(A, Wt, 1536, chunkRows, rowBase, colBase, tid, As, Bs, acc);
    EPI_SETUP
    int wc = wv << 5;
#pragma unroll
    for (int bt = 0; bt < 2; bt++) {
        int col = colBase + wc + bt * 16 + n16;
        float bcol = bias[col];
#pragma unroll
        for (int rt = 0; rt < 4; rt++)
#pragma unroll
        for (int reg = 0; reg < 4; reg++) {
            int rl = rowBase + rt * 16 + quad * 4 + reg;
            int rg = rowOfs + rl;
            if (rl < chunkRows && rg < LTOT) {
                size_t idx = (size_t)rg * C_DIM + col;
                out[idx] = acc[rt][bt][reg] + bcol + u2f(x2[idx]);
            }
        }
    }
}

// ---------------------------------------------------------------------------
// Kernel 3: MFMA flash attention. One 256-thread block (4 waves) per
// (head, window). K is NOT staged in LDS (fragment is contiguous in Kb's
// (n,d) layout; 22 KB/block K-panel is L2-resident). V stays in LDS.
// LDS: Vt 23040 + rp16 4400 + code 704 + Pb 4608 = 32752 B.
// launch_bounds(256,2): do NOT over-constrain the allocator -- (256,4)
// clamped VGPR to 64 and spilled the 88-reg S-state to scratch (R2/R6
// lesson: FETCH exploded to 250 MB). With (256,2) the allocator picks
// ~120 VGPR (<=128), so occupancy is still 4 blocks/CU via the LDS cap.
// ---------------------------------------------------------------------------
#define VP  360    // Vt row stride (u16), 720 B: 16B-aligned, 8-bank spread
#define PBS 36     // Pb row stride (u16), 72 B: 8B-aligned (read as 2xb64)

__global__ __launch_bounds__(256, 2) void k_attn(
    const u16* __restrict__ qW, const u16* __restrict__ Kb, const u16* __restrict__ Vb,
    const float* __restrict__ rpb, u16* __restrict__ oT)
{
    __shared__ __align__(16) u16 Vt[32 * VP];        // 23040 B
    __shared__ __align__(16) u16 rp16[2200];         //  4400 B
    __shared__ __align__(16) u16 code[352];          //   704 B
    __shared__ __align__(16) u16 Pb[4 * 16 * PBS];   //  4608 B

    const int h = blockIdx.x, w = blockIdx.y;
    const int tid = threadIdx.x;
    const int lane = tid & 63, wv = tid >> 6;
    const int m16 = lane & 15, quad = lane >> 4;
    const size_t base = ((size_t)(w * NHEAD + h)) * NTOK * HD;
    const u16* Kg = Kb + base;

    // V transposed [d][col], col = 32*kb + 2*j (token kb*32+j) | +1 (token +16).
    for (int t = tid; t < 704; t += 256) {
        int dg = t / 176, rem = t - dg * 176;
        int kb = rem >> 4, j = rem & 15;
        int n0 = kb * 32 + j, n1 = n0 + 16;
        uint4 uA = make_uint4(0, 0, 0, 0), uB = make_uint4(0, 0, 0, 0);
        if (n0 < NTOK) uA = *(const uint4*)(Vb + base + n0 * HD + dg * 8);
        if (n1 < NTOK) uB = *(const uint4*)(Vb + base + n1 * HD + dg * 8);
        int d0 = dg * 8, colu = kb * 32 + 2 * j;
        unsigned int pk0 = (uA.x & 0xffffu) | (uB.x << 16);
        unsigned int pk1 = (uA.x >> 16)     | (uB.x & 0xffff0000u);
        unsigned int pk2 = (uA.y & 0xffffu) | (uB.y << 16);
        unsigned int pk3 = (uA.y >> 16)     | (uB.y & 0xffff0000u);
        unsigned int pk4 = (uA.z & 0xffffu) | (uB.z << 16);
        unsigned int pk5 = (uA.z >> 16)     | (uB.z & 0xffff0000u);
        unsigned int pk6 = (uA.w & 0xffffu) | (uB.w << 16);
        unsigned int pk7 = (uA.w >> 16)     | (uB.w & 0xffff0000u);
        *(unsigned int*)&Vt[(d0 + 0) * VP + colu] = pk0;
        *(unsigned int*)&Vt[(d0 + 1) * VP + colu] = pk1;
        *(unsigned int*)&Vt[(d0 + 2) * VP + colu] = pk2;
        *(unsigned int*)&Vt[(d0 + 3) * VP + colu] = pk3;
        *(unsigned int*)&Vt[(d0 + 4) * VP + colu] = pk4;
        *(unsigned int*)&Vt[(d0 + 5) * VP + colu] = pk5;
        *(unsigned int*)&Vt[(d0 + 6) * VP + colu] = pk6;
        *(unsigned int*)&Vt[(d0 + 7) * VP + colu] = pk7;
    }
    // bias table in log2 units
    for (int t = tid; t < 2200; t += 256)
        rp16[t] = (t < 2197) ? f2b(rpb[t * NHEAD + h] * 1.4426950408889634f) : (u16)0;
    for (int t = tid; t < 352; t += 256) {
        int z = t / 49, rem = t % 49, y = rem / 7, x = rem % 7;
        code[t] = (t < NTOK) ? (u16)(z * 169 + y * 13 + x) : (u16)1098;
    }
    __syncthreads();

    const float scale = 0.2550348772f;  // (1/sqrt(32)) * log2(e)
    u16* myP = Pb + wv * 16 * PBS;

    for (int qt = wv; qt < 22; qt += 4) {
        int qbase = qt * 16;
        int qrow = min(qbase + m16, NTOK - 1);
        s16x8 qf = *(const s16x8*)(qW + ((size_t)(w * NTOK + qrow)) * C_DIM
                                       + h * HD + quad * 8);
        int qcv[4];
#pragma unroll
        for (int i = 0; i < 4; i++) qcv[i] = code[qbase + quad * 4 + i];

        f32x4 S0[11], S1[11];
        float mx[4] = {-1e30f, -1e30f, -1e30f, -1e30f};

#pragma unroll
        for (int ks = 0; ks < 11; ks++) {
            int kbase = ks * 32;
            int kt0 = kbase + m16, kt1 = kt0 + 16;
            // K fragments straight from global (L2-resident); kt1 rows past
            // NTOK read garbage within the workspace -- masked by k1ok below.
            s16x8 kf0 = *(const s16x8*)(Kg + (size_t)kt0 * HD + quad * 8);
            s16x8 kf1 = *(const s16x8*)(Kg + (size_t)kt1 * HD + quad * 8);
            f32x4 z = {0.f, 0.f, 0.f, 0.f};
            f32x4 sA = __builtin_amdgcn_mfma_f32_16x16x32_bf16(qf, kf0, z, 0, 0, 0);
            f32x4 sB = __builtin_amdgcn_mfma_f32_16x16x32_bf16(qf, kf1, z, 0, 0, 0);
            int kc0 = code[kt0], kc1 = code[kt1];
            bool k1ok = (ks < 10) || (kt1 < NTOK);
#pragma unroll
            for (int i = 0; i < 4; i++) {
                float b0 = u2f(rp16[qcv[i] - kc0 + 1098]);
                float b1 = u2f(rp16[qcv[i] - kc1 + 1098]);
                float sa = fmaf(sA[i], scale, b0);
                float sb = k1ok ? fmaf(sB[i], scale, b1) : -1e30f;
                S0[ks][i] = sa;
                S1[ks][i] = sb;
                mx[i] = fmaxf(mx[i], fmaxf(sa, sb));
            }
        }
#pragma unroll
        for (int i = 0; i < 4; i++) {
            float v = mx[i];
            v = fmaxf(v, __shfl_xor(v, 1));
            v = fmaxf(v, __shfl_xor(v, 2));
            v = fmaxf(v, __shfl_xor(v, 4));
            v = fmaxf(v, __shfl_xor(v, 8));
            mx[i] = v;
        }

        f32x4 O0 = {}, O1 = {};
        float l[4] = {};
#pragma unroll
        for (int ks = 0; ks < 11; ks++) {
            int kbase = ks * 32;
#pragma unroll
            for (int i = 0; i < 4; i++) {
                float pa = exp2_hw(S0[ks][i] - mx[i]);   // col 2*m16   (k=m16)
                float pb = exp2_hw(S1[ks][i] - mx[i]);   // col 2*m16+1 (k=16+m16)
                l[i] += pa + pb;
                *(unsigned int*)&myP[(quad * 4 + i) * PBS + 2 * m16] = pk_bf16(pa, pb);
            }
            s16x4 plo = *(const s16x4*)&myP[m16 * PBS + quad * 8];
            s16x4 phi = *(const s16x4*)&myP[m16 * PBS + quad * 8 + 4];
            s16x8 pf  = __builtin_shufflevector(plo, phi, 0, 1, 2, 3, 4, 5, 6, 7);
            s16x8 vf0 = *(const s16x8*)&Vt[m16 * VP + kbase + quad * 8];
            s16x8 vf1 = *(const s16x8*)&Vt[(16 + m16) * VP + kbase + quad * 8];
            O0 = __builtin_amdgcn_mfma_f32_16x16x32_bf16(pf, vf0, O0, 0, 0, 0);
            O1 = __builtin_amdgcn_mfma_f32_16x16x32_bf16(pf, vf1, O1, 0, 0, 0);
        }
#pragma unroll
        for (int i = 0; i < 4; i++) {
            float v = l[i];
            v += __shfl_xor(v, 1);
            v += __shfl_xor(v, 2);
            v += __shfl_xor(v, 4);
            v += __shfl_xor(v, 8);
            l[i] = v;
        }

        int wd = w >> 4, wh = (w >> 2) & 3, wwi = w & 3;
#pragma unroll
        for (int i = 0; i < 4; i++) {
            int q = qbase + quad * 4 + i;
            if (q < NTOK) {
                float rl = __builtin_amdgcn_rcpf(l[i]);
                int qz = q / 49, qrem = q % 49, qy = qrem / 7, qx = qrem % 7;
                size_t tok = ((size_t)(wd * 7 + qz) * SIDE + (wh * 7 + qy)) * SIDE
                             + (wwi * 7 + qx);
                u16* op = oT + tok * C_DIM + h * HD;
                op[m16]      = f2b(O0[i] * rl);
                op[16 + m16] = f2b(O1[i] * rl);
            }
        }
    }
}

// ---------------------------------------------------------------------------
// Workspace layout unchanged.
// ---------------------------------------------------------------------------
extern "C" void kernel_launch(void* const* d_in, const int* in_sizes, int n_in,
                              void* d_out, int out_size, void* d_ws, size_t ws_size,
                              hipStream_t stream)
{
    const float* skip = (const float*)d_in[0];
    const float* xup  = (const float*)d_in[1];
    const float* ln1g = (const float*)d_in[5];
    const float* ln1b = (const float*)d_in[6];
    const float* kvw  = (const float*)d_in[7];
    const float* kvb  = (const float*)d_in[8];
    const float* rpb  = (const float*)d_in[9];
    const float* pw   = (const float*)d_in[10];
    const float* pb   = (const float*)d_in[11];
    const float* ln2g = (const float*)d_in[12];
    const float* ln2b = (const float*)d_in[13];
    const float* w1   = (const float*)d_in[14];
    const float* b1   = (const float*)d_in[15];
    const float* w2   = (const float*)d_in[16];
    const float* b2   = (const float*)d_in[17];
    float* out = (float*)d_out;

    char* ws = (char*)d_ws;
    const size_t BUFB = (size_t)LTOT * C_DIM * 2;   // 16,859,136 B
    const size_t WTB  = 589824 + 294912 + 1179648 + 1179648;  // 3,244,032 B
    u16* skW = (u16*)(ws);
    u16* qW  = (u16*)(ws + BUFB);
    u16* Kb  = (u16*)(ws + 2 * BUFB);
    u16* Vb  = (u16*)(ws + 3 * BUFB);
    u16* oT  = (u16*)(ws);                  // overlays skW (dead)
    u16* x2  = (u16*)(ws + BUFB);           // overlays qW (dead)
    u16* lnx = (u16*)(ws + 2 * BUFB);       // overlays Kb (dead)
    char* wt = ws + 4 * BUFB;
    u16* kvWt = (u16*)(wt);
    u16* pWt  = (u16*)(wt + 589824);
    u16* w1t  = (u16*)(wt + 589824 + 294912);
    u16* w2t  = (u16*)(wt + 589824 + 294912 + 1179648);
    u16* res  = (u16*)d_out;                // scratch in d_out (dead until mlp2)

    const size_t used = 4 * BUFB + WTB;
    const size_t blkBytes = 128 * 1536 * 2;         // 393,216 B
    size_t tailCap = (ws_size > used) ? (ws_size - used) / blkBytes : 0;
    int chunkBlocks;
    u16* h1c;
    if (tailCap >= 43) {
        chunkBlocks = tailCap < 172 ? (int)tailCap : 172;
        h1c = (u16*)(ws + used);
    } else {
        chunkBlocks = 42;                            // fits in s3 (Vb, dead)
        h1c = (u16*)(ws + 3 * BUFB);
    }

    k_wt<<<dim3(6, 12), 256, 0, stream>>>(kvw, kvWt, 384, 768);
    k_wt<<<dim3(6, 6),  256, 0, stream>>>(pw,  pWt,  384, 384);
    k_wt<<<dim3(6, 24), 256, 0, stream>>>(w1,  w1t,  384, 1536);
    k_wt_pi<<<dim3(24, 6), 256, 0, stream>>>(w2, w2t, 1536, 384);

    k_lnprep<<<LTOT / 4, 256, 0, stream>>>(skip, xup, ln1g, ln1b, skW, qW, res);
    k_gemm_kv<<<dim3(172, 6), 256, 0, stream>>>(skW, kvWt, kvb, Kb, Vb);
    k_attn<<<dim3(NHEAD, NWIN), 256, 0, stream>>>(qW, Kb, Vb, rpb, oT);
    k_gemm_proj<<<dim3(343, 3), 256, 0, stream>>>(oT, pWt, pb, res, x2);
    k_ln2<<<LTOT / 4, 256, 0, stream>>>(x2, ln2g, ln2b, lnx);
    for (int b0 = 0; b0 < 172; b0 += chunkBlocks) {
        int nb = (172 - b0) < chunkBlocks ? (172 - b0) : chunkBlocks;
        int rowOfs = b0 * 128;
        int chunkRows = nb * 128;
        if (rowOfs + chunkRows > LTOT) chunkRows = LTOT - rowOfs;
        int nb64 = (chunkRows + 63) / 64;
        k_gemm_mlp1<<<dim3(nb, 12), 256, 0, stream>>>(lnx, w1t, b1, h1c, rowOfs);
        k_gemm_mlp2<<<dim3(nb64, 3), 256, 0, stream>>>(h1c, w2t, b2, x2, out, rowOfs, chunkRows);
    }
}

// Round 8
// 423.078 us; speedup vs baseline: 1.1313x; 1.0326x over previous
//
#include <hip/hip_runtime.h>
#include <hip/hip_bf16.h>
#include <cstdint>

typedef unsigned short u16;
typedef short s16x8 __attribute__((ext_vector_type(8)));
typedef short s16x4 __attribute__((ext_vector_type(4)));
typedef float f32x4 __attribute__((ext_vector_type(4)));

#define C_DIM 384
#define NHEAD 12
#define HD    32
#define NTOK  343     // tokens per window (7^3)
#define NWIN  64
#define LTOT  21952   // 28^3
#define SIDE  28

__device__ __forceinline__ float u2f(u16 u) {
    return __uint_as_float(((unsigned int)u) << 16);
}
__device__ __forceinline__ u16 f2b(float f) {
    unsigned int u = __float_as_uint(f);
    return (u16)((u + 0x7fffu + ((u >> 16) & 1u)) >> 16);   // RNE
}
__device__ __forceinline__ float exp2_hw(float x) {
    float r;
    asm("v_exp_f32 %0, %1" : "=v"(r) : "v"(x));
    return r;
}
// pack two f32 -> two bf16 (RNE) in one op
__device__ __forceinline__ unsigned int pk_bf16(float lo, float hi) {
    unsigned int r;
    asm("v_cvt_pk_bf16_f32 %0, %1, %2" : "=v"(r) : "v"(lo), "v"(hi));
    return r;
}
// gelu tanh-approx: 0.5x(1+tanh(z)) == x / (1 + 2^(-2z*log2e))
__device__ __forceinline__ float gelu_fast(float x) {
    float e = exp2_hw(-2.3022083f * (x + 0.044715f * x * x * x));
    return x * __builtin_amdgcn_rcpf(1.f + e);
}

// ---------------------------------------------------------------------------
// Weight transpose + f32->bf16: Wt[n][k] = bf16(W[k][n]).  W is KxN row-major.
// ---------------------------------------------------------------------------
__global__ __launch_bounds__(256) void k_wt(
    const float* __restrict__ W, u16* __restrict__ Wt, int K, int N)
{
    __shared__ float T[64][65];
    int k0 = blockIdx.x * 64, n0 = blockIdx.y * 64;
    int t = threadIdx.x;
    int c = t & 63, rg = t >> 6;
#pragma unroll
    for (int i = 0; i < 16; i++) {
        int r = rg * 16 + i;
        T[r][c] = W[(size_t)(k0 + r) * N + n0 + c];
    }
    __syncthreads();
    int k = t & 63, ng = t >> 6;
#pragma unroll
    for (int i = 0; i < 16; i++) {
        int n = ng * 16 + i;
        Wt[(size_t)(n0 + n) * K + k0 + k] = f2b(T[k][n]);
    }
}

// Same, but the k (contraction) index is pi-permuted within each 128-block:
// j = k%128 = ct*16+n  ->  j' = 32*(ct>>1) + 2*n + (ct&1).
// Used for w2 so mlp1 can store h1 in pair-packed column order.
__global__ __launch_bounds__(256) void k_wt_pi(
    const float* __restrict__ W, u16* __restrict__ Wt, int K, int N)
{
    __shared__ float T[64][65];
    int k0 = blockIdx.x * 64, n0 = blockIdx.y * 64;
    int t = threadIdx.x;
    int c = t & 63, rg = t >> 6;
#pragma unroll
    for (int i = 0; i < 16; i++) {
        int r = rg * 16 + i;
        T[r][c] = W[(size_t)(k0 + r) * N + n0 + c];
    }
    __syncthreads();
    int k = t & 63, ng = t >> 6;
    int kg = k0 + k;
    int j = kg & 127, ct = j >> 4, nn = j & 15;
    int kp = (kg & ~127) | ((ct >> 1) << 5) | (nn << 1) | (ct & 1);
#pragma unroll
    for (int i = 0; i < 16; i++) {
        int n = ng * 16 + i;
        Wt[(size_t)(n0 + n) * K + kp] = f2b(T[k][n]);
    }
}

// ---------------------------------------------------------------------------
// Bias plane precompute: biasPl[h][q][k] = bf16(rpb[relidx(q,k)][h] * log2e),
// q,k in [0,352); rows/cols >= NTOK clamped (values masked downstream).
// 12*352*352*2 B = 2.97 MB; per-head 248 KB -> L2-resident during attn.
// ---------------------------------------------------------------------------
__global__ __launch_bounds__(256) void k_bias(
    const float* __restrict__ rpb, u16* __restrict__ biasPl)
{
    int h = blockIdx.x, q = blockIdx.y;
    int qc = min(q, NTOK - 1);
    int qz = qc / 49, qrem = qc % 49, qy = qrem / 7, qx = qrem % 7;
    int cq = qz * 169 + qy * 13 + qx;
    u16* dst = biasPl + ((size_t)h * 352 + q) * 352;
    for (int k = threadIdx.x; k < 352; k += 256) {
        int kc = min(k, NTOK - 1);
        int kz = kc / 49, krem = kc % 49, ky = krem / 7, kx = krem % 7;
        int ck = kz * 169 + ky * 13 + kx;
        dst[k] = f2b(rpb[(size_t)(cq - ck + 1098) * NHEAD + h] * 1.4426950408889634f);
    }
}

// ---------------------------------------------------------------------------
// Kernel 1: dual LayerNorm + window partition -> bf16; also res = bf16(skip+xup)
// qW is consumed ONLY by attention: bake the softmax scale (1/sqrt(32)*log2e)
// into it so the QK^T MFMA needs no post-scale.
// ---------------------------------------------------------------------------
#define QSCALE 0.2550348772f

__global__ __launch_bounds__(256) void k_lnprep(
    const float* __restrict__ skip, const float* __restrict__ xup,
    const float* __restrict__ g, const float* __restrict__ bta,
    u16* __restrict__ skW, u16* __restrict__ qW, u16* __restrict__ res)
{
    int t = blockIdx.x * 4 + (threadIdx.x >> 6);
    int lane = threadIdx.x & 63;
    const float* ps = skip + (size_t)t * C_DIM;
    const float* px = xup + (size_t)t * C_DIM;
    float vs[6], vx[6];
    float s1 = 0.f, s2 = 0.f, x1 = 0.f, x2 = 0.f;
#pragma unroll
    for (int j = 0; j < 6; j++) {
        float a = ps[lane + j * 64];
        float b = px[lane + j * 64];
        vs[j] = a; vx[j] = b;
        s1 += a; s2 += a * a; x1 += b; x2 += b * b;
    }
#pragma unroll
    for (int off = 32; off; off >>= 1) {
        s1 += __shfl_xor(s1, off);
        s2 += __shfl_xor(s2, off);
        x1 += __shfl_xor(x1, off);
        x2 += __shfl_xor(x2, off);
    }
    float ms = s1 * (1.f / 384.f), mx = x1 * (1.f / 384.f);
    float rs = rsqrtf(fmaxf(s2 * (1.f / 384.f) - ms * ms, 0.f) + 1e-5f);
    float rx = rsqrtf(fmaxf(x2 * (1.f / 384.f) - mx * mx, 0.f) + 1e-5f);
    int d = t / 784, rem = t % 784, hh = rem / 28, ww = rem % 28;
    int win = (d / 7) * 16 + (hh / 7) * 4 + (ww / 7);
    int n = (d % 7) * 49 + (hh % 7) * 7 + (ww % 7);
    size_t dst = ((size_t)(win * NTOK + n)) * C_DIM + lane;
    size_t td  = (size_t)t * C_DIM + lane;
#pragma unroll
    for (int j = 0; j < 6; j++) {
        int c = lane + j * 64;
        float gg = g[c], bb = bta[c];
        skW[dst + j * 64] = f2b((vs[j] - ms) * rs * gg + bb);
        qW[dst + j * 64]  = f2b(((vx[j] - mx) * rx * gg + bb) * QSCALE);
        res[td + j * 64]  = f2b(vs[j] + vx[j]);
    }
}

// ---------------------------------------------------------------------------
// Kernel 5: LayerNorm of x2 (bf16) -> lnx (bf16).
// ---------------------------------------------------------------------------
__global__ __launch_bounds__(256) void k_ln2(
    const u16* __restrict__ x2, const float* __restrict__ g,
    const float* __restrict__ bta, u16* __restrict__ lnx)
{
    int t = blockIdx.x * 4 + (threadIdx.x >> 6);
    int lane = threadIdx.x & 63;
    const u16* p = x2 + (size_t)t * C_DIM;
    float v[6];
    float s1 = 0.f, s2 = 0.f;
#pragma unroll
    for (int j = 0; j < 6; j++) {
        float a = u2f(p[lane + j * 64]);
        v[j] = a; s1 += a; s2 += a * a;
    }
#pragma unroll
    for (int off = 32; off; off >>= 1) {
        s1 += __shfl_xor(s1, off);
        s2 += __shfl_xor(s2, off);
    }
    float m = s1 * (1.f / 384.f);
    float r = rsqrtf(fmaxf(s2 * (1.f / 384.f) - m * m, 0.f) + 1e-5f);
    size_t dst = (size_t)t * C_DIM + lane;
#pragma unroll
    for (int j = 0; j < 6; j++) {
        int c = lane + j * 64;
        lnx[dst + j * 64] = f2b((v[j] - m) * r * g[c] + bta[c]);
    }
}

// ---------------------------------------------------------------------------
// 128x128 MFMA GEMM core: wave = 64 rows x 64 cols (2x2 wave grid).
// Per 32-K step per wave: 4 A + 4 B ds_read_b128, 16 MFMA.
// ---------------------------------------------------------------------------
#define BPAD 40   // LDS row stride in u16 (32 data + 8 pad; 2-way banks)

__device__ __forceinline__ void gemm128(
    const u16* __restrict__ A, const u16* __restrict__ Bt, int K, int M,
    int rowBase, int colBase, int tid,
    u16 (*As)[BPAD], u16 (*Bs)[BPAD], f32x4 acc[4][4])
{
    const int sr  = tid >> 2;
    const int scg = (tid & 3) << 3;
    const int lane = tid & 63, wv = tid >> 6;
    const int m16 = lane & 15, quad = lane >> 4;
    const int wr = (wv >> 1) << 6, wc = (wv & 1) << 6;

    int ra0 = min(rowBase + sr, M - 1);
    int ra1 = min(rowBase + 64 + sr, M - 1);
    const u16* pa0 = A + (size_t)ra0 * K + scg;
    const u16* pa1 = A + (size_t)ra1 * K + scg;
    const u16* pb0 = Bt + (size_t)(colBase + sr) * K + scg;
    const u16* pb1 = Bt + (size_t)(colBase + 64 + sr) * K + scg;

    uint4 a0 = *(const uint4*)pa0, a1 = *(const uint4*)pa1;
    uint4 b0 = *(const uint4*)pb0, b1 = *(const uint4*)pb1;

    for (int kk = 0; kk < K; kk += 32) {
        *(uint4*)&As[sr][scg]      = a0;
        *(uint4*)&As[64 + sr][scg] = a1;
        *(uint4*)&Bs[sr][scg]      = b0;
        *(uint4*)&Bs[64 + sr][scg] = b1;
        __syncthreads();
        if (kk + 32 < K) {
            a0 = *(const uint4*)(pa0 + kk + 32);
            a1 = *(const uint4*)(pa1 + kk + 32);
            b0 = *(const uint4*)(pb0 + kk + 32);
            b1 = *(const uint4*)(pb1 + kk + 32);
        }
        s16x8 af[4], bf[4];
#pragma unroll
        for (int rt = 0; rt < 4; rt++)
            af[rt] = *(const s16x8*)&As[wr + rt * 16 + m16][quad * 8];
#pragma unroll
        for (int bt = 0; bt < 4; bt++)
            bf[bt] = *(const s16x8*)&Bs[wc + bt * 16 + m16][quad * 8];
#pragma unroll
        for (int rt = 0; rt < 4; rt++)
#pragma unroll
        for (int bt = 0; bt < 4; bt++)
            acc[rt][bt] = __builtin_amdgcn_mfma_f32_16x16x32_bf16(af[rt], bf[bt], acc[rt][bt], 0, 0, 0);
        __syncthreads();
    }
}

// ---------------------------------------------------------------------------
// 64x128 MFMA GEMM core, double-buffered LDS, ONE barrier per 32-K phase,
// wave = 64 rows x 32 cols. Two named register sets; each load issued
// 2 phases before its LDS write. K % 64 == 0 required.
// ---------------------------------------------------------------------------
__device__ __forceinline__ void gemm64_db(
    const u16* __restrict__ A, const u16* __restrict__ Bt, int K, int M,
    int rowBase, int colBase, int tid,
    u16 (*As)[BPAD], u16 (*Bs)[BPAD], f32x4 acc[4][2])
{
    const int sr  = tid >> 2;          // 0..63 staging row
    const int scg = (tid & 3) << 3;    // u16 col offset {0,8,16,24}
    const int lane = tid & 63, wv = tid >> 6;
    const int m16 = lane & 15, quad = lane >> 4;
    const int wc = wv << 5;            // wave's 32-col slice

    int ra = min(rowBase + sr, M - 1);
    const u16* pa  = A + (size_t)ra * K + scg;
    const u16* pb0 = Bt + (size_t)(colBase + sr) * K + scg;
    const u16* pb1 = Bt + (size_t)(colBase + 64 + sr) * K + scg;

    uint4 aA = *(const uint4*)pa,        bA0 = *(const uint4*)pb0,        bA1 = *(const uint4*)pb1;
    uint4 aB = *(const uint4*)(pa + 32), bB0 = *(const uint4*)(pb0 + 32), bB1 = *(const uint4*)(pb1 + 32);

    // prologue: stage tile 0 into buf0, refill set A with tile 64
    *(uint4*)&As[sr][scg]      = aA;
    *(uint4*)&Bs[sr][scg]      = bA0;
    *(uint4*)&Bs[64 + sr][scg] = bA1;
    if (64 < K) {
        aA  = *(const uint4*)(pa + 64);
        bA0 = *(const uint4*)(pb0 + 64);
        bA1 = *(const uint4*)(pb1 + 64);
    }
    __syncthreads();

    for (int kk = 0; kk < K; kk += 64) {
        // ---- phase A: compute tile kk (buf0); stage tile kk+32 -> buf1 ----
        *(uint4*)&As[64 + sr][scg]  = aB;
        *(uint4*)&Bs[128 + sr][scg] = bB0;
        *(uint4*)&Bs[192 + sr][scg] = bB1;
        if (kk + 96 < K) {
            aB  = *(const uint4*)(pa  + kk + 96);
            bB0 = *(const uint4*)(pb0 + kk + 96);
            bB1 = *(const uint4*)(pb1 + kk + 96);
        }
        {
            s16x8 af[4], bf[2];
#pragma unroll
            for (int rt = 0; rt < 4; rt++)
                af[rt] = *(const s16x8*)&As[rt * 16 + m16][quad * 8];
#pragma unroll
            for (int bt = 0; bt < 2; bt++)
                bf[bt] = *(const s16x8*)&Bs[wc + bt * 16 + m16][quad * 8];
#pragma unroll
            for (int rt = 0; rt < 4; rt++)
#pragma unroll
            for (int bt = 0; bt < 2; bt++)
                acc[rt][bt] = __builtin_amdgcn_mfma_f32_16x16x32_bf16(af[rt], bf[bt], acc[rt][bt], 0, 0, 0);
        }
        __syncthreads();
        // ---- phase B: compute tile kk+32 (buf1); stage tile kk+64 -> buf0 ----
        if (kk + 64 < K) {
            *(uint4*)&As[sr][scg]      = aA;
            *(uint4*)&Bs[sr][scg]      = bA0;
            *(uint4*)&Bs[64 + sr][scg] = bA1;
        }
        if (kk + 128 < K) {
            aA  = *(const uint4*)(pa  + kk + 128);
            bA0 = *(const uint4*)(pb0 + kk + 128);
            bA1 = *(const uint4*)(pb1 + kk + 128);
        }
        {
            s16x8 af[4], bf[2];
#pragma unroll
            for (int rt = 0; rt < 4; rt++)
                af[rt] = *(const s16x8*)&As[64 + rt * 16 + m16][quad * 8];
#pragma unroll
            for (int bt = 0; bt < 2; bt++)
                bf[bt] = *(const s16x8*)&Bs[128 + wc + bt * 16 + m16][quad * 8];
#pragma unroll
            for (int rt = 0; rt < 4; rt++)
#pragma unroll
            for (int bt = 0; bt < 2; bt++)
                acc[rt][bt] = __builtin_amdgcn_mfma_f32_16x16x32_bf16(af[rt], bf[bt], acc[rt][bt], 0, 0, 0);
        }
        __syncthreads();
    }
}

#define EPI_SETUP \
    int lane = tid & 63, wv = tid >> 6, quad = lane >> 4, n16 = lane & 15;

// KV projection (K=384, N=768): scatter to K/V (w,head,n,d) bf16.
__global__ __launch_bounds__(256) void k_gemm_kv(
    const u16* __restrict__ A, const u16* __restrict__ Wt, const float* __restrict__ bias,
    u16* __restrict__ Kb, u16* __restrict__ Vb)
{
    __shared__ __align__(16) u16 As[128][BPAD];
    __shared__ __align__(16) u16 Bs[128][BPAD];
    f32x4 acc[4][4] = {};
    int tid = threadIdx.x;
    int rowBase = blockIdx.x * 128, colBase = blockIdx.y * 128;
    gemm128(A, Wt, 384, LTOT, rowBase, colBase, tid, As, Bs, acc);
    EPI_SETUP
    int wr = (wv >> 1) << 6, wc = (wv & 1) << 6;
#pragma unroll
    for (int bt = 0; bt < 4; bt++) {
        int col = colBase + wc + bt * 16 + n16;
        float bcol = bias[col];
        int isv = col >= 384;
        int remc = col - (isv ? 384 : 0);
        int hh = remc >> 5, dd = remc & 31;
#pragma unroll
        for (int rt = 0; rt < 4; rt++)
#pragma unroll
        for (int reg = 0; reg < 4; reg++) {
            int r = rowBase + wr + rt * 16 + quad * 4 + reg;
            if (r < LTOT) {
                int w = r / NTOK, nn = r % NTOK;
                size_t dst = ((size_t)((w * NHEAD + hh) * NTOK + nn)) * HD + dd;
                (isv ? Vb : Kb)[dst] = f2b(acc[rt][bt][reg] + bcol);
            }
        }
    }
}

// Output projection (K=384, N=384) + bias + residual res (bf16) -> x2 bf16.
__global__ __launch_bounds__(256) void k_gemm_proj(
    const u16* __restrict__ A, const u16* __restrict__ Wt, const float* __restrict__ bias,
    const u16* __restrict__ res, u16* __restrict__ x2)
{
    __shared__ __align__(16) u16 As[128][BPAD];   // 2 bufs x 64 rows
    __shared__ __align__(16) u16 Bs[256][BPAD];   // 2 bufs x 128 rows
    f32x4 acc[4][2] = {};
    int tid = threadIdx.x;
    int rowBase = blockIdx.x * 64, colBase = blockIdx.y * 128;
    gemm64_db(A, Wt, 384, LTOT, rowBase, colBase, tid, As, Bs, acc);
    EPI_SETUP
    int wc = wv << 5;
#pragma unroll
    for (int bt = 0; bt < 2; bt++) {
        int col = colBase + wc + bt * 16 + n16;
        float bcol = bias[col];
#pragma unroll
        for (int rt = 0; rt < 4; rt++)
#pragma unroll
        for (int reg = 0; reg < 4; reg++) {
            int r = rowBase + rt * 16 + quad * 4 + reg;
            if (r < LTOT) {
                size_t idx = (size_t)r * C_DIM + col;
                x2[idx] = f2b(acc[rt][bt][reg] + bcol + u2f(res[idx]));
            }
        }
    }
}

// MLP1 (K=384, N=1536) + bias + gelu -> h1 chunk bf16, pair-packed columns:
// within each 128-col block, cols (32p+n, 32p+16+n) -> packed u32 at 32p+2n.
// w2t is permuted identically (k_wt_pi) so mlp2 is unchanged.
__global__ __launch_bounds__(256) void k_gemm_mlp1(
    const u16* __restrict__ A, const u16* __restrict__ Wt, const float* __restrict__ bias,
    u16* __restrict__ h1c, int rowOfs)
{
    __shared__ __align__(16) u16 As[128][BPAD];
    __shared__ __align__(16) u16 Bs[128][BPAD];
    f32x4 acc[4][4] = {};
    int tid = threadIdx.x;
    int rowBase = rowOfs + blockIdx.x * 128, colBase = blockIdx.y * 128;
    gemm128(A, Wt, 384, LTOT, rowBase, colBase, tid, As, Bs, acc);
    EPI_SETUP
    int wr = (wv >> 1) << 6;
#pragma unroll
    for (int p2 = 0; p2 < 2; p2++) {
        int p = (wv & 1) * 2 + p2;            // global pair index 0..3
        int col0 = colBase + p * 32 + n16;    // ct = 2p
        int col1 = col0 + 16;                 // ct = 2p+1
        float bc0 = bias[col0], bc1 = bias[col1];
        int dcol = colBase + p * 32 + 2 * n16;
#pragma unroll
        for (int rt = 0; rt < 4; rt++)
#pragma unroll
        for (int reg = 0; reg < 4; reg++) {
            int r = rowBase + wr + rt * 16 + quad * 4 + reg;
            if (r < LTOT) {
                size_t rl = (size_t)(r - rowOfs);
                float v0 = gelu_fast(acc[rt][2 * p2][reg] + bc0);
                float v1 = gelu_fast(acc[rt][2 * p2 + 1][reg] + bc1);
                *(unsigned int*)&h1c[rl * 1536 + dcol] = pk_bf16(v0, v1);
            }
        }
    }
}

// MLP2 (K=1536 permuted, N=384) + bias + residual x2 (bf16) -> out f32 (final).
__global__ __launch_bounds__(256) void k_gemm_mlp2(
    const u16* __restrict__ A, const u16* __restrict__ Wt, const float* __restrict__ bias,
    const u16* __restrict__ x2, float* __restrict__ out, int rowOfs, int chunkRows)
{
    __shared__ __align__(16) u16 As[128][BPAD];   // 2 bufs x 64 rows
    __shared__ __align__(16) u16 Bs[256][BPAD];   // 2 bufs x 128 rows
    f32x4 acc[4][2] = {};
    int tid = threadIdx.x;
    int rowBase = blockIdx.x * 64, colBase = blockIdx.y * 128;   // local rows
    gemm64_db(A, Wt, 1536, chunkRows, rowBase, colBase, tid, As, Bs, acc);
    EPI_SETUP
    int wc = wv << 5;
#pragma unroll
    for (int bt = 0; bt < 2; bt++) {
        int col = colBase + wc + bt * 16 + n16;
        float bcol = bias[col];
#pragma unroll
        for (int rt = 0; rt < 4; rt++)
#pragma unroll
        for (int reg = 0; reg < 4; reg++) {
            int rl = rowBase + rt * 16 + quad * 4 + reg;
            int rg = rowOfs + rl;
            if (rl < chunkRows && rg < LTOT) {
                size_t idx = (size_t)rg * C_DIM + col;
                out[idx] = acc[rt][bt][reg] + bcol + u2f(x2[idx]);
            }
        }
    }
}

// ---------------------------------------------------------------------------
// Kernel 3: MFMA flash attention. One 256-thread block (4 waves) per
// (head, window). K read straight from global (L2-resident); bias read
// straight from the precomputed biasPl plane as coalesced scalar loads and
// fed as the MFMA C-operand (scale pre-baked into qW). NO pass-1 LDS traffic.
// V stays in LDS (transposed+pair-packed). LDS: Vt 23040 + Pb 4608 = 27648 B.
// launch_bounds(256,2): R2/R6 lesson -- tighter bounds spill the S-state.
// ---------------------------------------------------------------------------
#define VP  360    // Vt row stride (u16), 720 B: 16B-aligned, 8-bank spread
#define PBS 36     // Pb row stride (u16), 72 B: 8B-aligned (read as 2xb64)

__global__ __launch_bounds__(256, 2) void k_attn(
    const u16* __restrict__ qW, const u16* __restrict__ Kb, const u16* __restrict__ Vb,
    const u16* __restrict__ biasPl, u16* __restrict__ oT)
{
    __shared__ __align__(16) u16 Vt[32 * VP];        // 23040 B
    __shared__ __align__(16) u16 Pb[4 * 16 * PBS];   //  4608 B

    const int h = blockIdx.x, w = blockIdx.y;
    const int tid = threadIdx.x;
    const int lane = tid & 63, wv = tid >> 6;
    const int m16 = lane & 15, quad = lane >> 4;
    const size_t base = ((size_t)(w * NHEAD + h)) * NTOK * HD;
    const u16* Kg = Kb + base;

    // V transposed [d][col], col = 32*kb + 2*j (token kb*32+j) | +1 (token +16).
    for (int t = tid; t < 704; t += 256) {
        int dg = t / 176, rem = t - dg * 176;
        int kb = rem >> 4, j = rem & 15;
        int n0 = kb * 32 + j, n1 = n0 + 16;
        uint4 uA = make_uint4(0, 0, 0, 0), uB = make_uint4(0, 0, 0, 0);
        if (n0 < NTOK) uA = *(const uint4*)(Vb + base + n0 * HD + dg * 8);
        if (n1 < NTOK) uB = *(const uint4*)(Vb + base + n1 * HD + dg * 8);
        int d0 = dg * 8, colu = kb * 32 + 2 * j;
        unsigned int pk0 = (uA.x & 0xffffu) | (uB.x << 16);
        unsigned int pk1 = (uA.x >> 16)     | (uB.x & 0xffff0000u);
        unsigned int pk2 = (uA.y & 0xffffu) | (uB.y << 16);
        unsigned int pk3 = (uA.y >> 16)     | (uB.y & 0xffff0000u);
        unsigned int pk4 = (uA.z & 0xffffu) | (uB.z << 16);
        unsigned int pk5 = (uA.z >> 16)     | (uB.z & 0xffff0000u);
        unsigned int pk6 = (uA.w & 0xffffu) | (uB.w << 16);
        unsigned int pk7 = (uA.w >> 16)     | (uB.w & 0xffff0000u);
        *(unsigned int*)&Vt[(d0 + 0) * VP + colu] = pk0;
        *(unsigned int*)&Vt[(d0 + 1) * VP + colu] = pk1;
        *(unsigned int*)&Vt[(d0 + 2) * VP + colu] = pk2;
        *(unsigned int*)&Vt[(d0 + 3) * VP + colu] = pk3;
        *(unsigned int*)&Vt[(d0 + 4) * VP + colu] = pk4;
        *(unsigned int*)&Vt[(d0 + 5) * VP + colu] = pk5;
        *(unsigned int*)&Vt[(d0 + 6) * VP + colu] = pk6;
        *(unsigned int*)&Vt[(d0 + 7) * VP + colu] = pk7;
    }
    __syncthreads();

    u16* myP = Pb + wv * 16 * PBS;

    for (int qt = wv; qt < 22; qt += 4) {
        int qbase = qt * 16;
        int qrow = min(qbase + m16, NTOK - 1);
        s16x8 qf = *(const s16x8*)(qW + ((size_t)(w * NTOK + qrow)) * C_DIM
                                       + h * HD + quad * 8);
        // bias rows for this lane's 4 q values (coalesced u16 loads over m16)
        const u16* bp = biasPl + ((size_t)h * 352 + qbase + quad * 4) * 352;

        f32x4 S0[11], S1[11];
        float mx[4] = {-1e30f, -1e30f, -1e30f, -1e30f};

#pragma unroll
        for (int ks = 0; ks < 11; ks++) {
            int kbase = ks * 32;
            int kt0 = kbase + m16, kt1 = kt0 + 16;
            // K fragments straight from global (L2-resident); kt1 rows past
            // NTOK read garbage within the workspace -- masked by k1ok below.
            s16x8 kf0 = *(const s16x8*)(Kg + (size_t)kt0 * HD + quad * 8);
            s16x8 kf1 = *(const s16x8*)(Kg + (size_t)kt1 * HD + quad * 8);
            f32x4 c0, c1;
#pragma unroll
            for (int i = 0; i < 4; i++) {
                c0[i] = u2f(bp[i * 352 + kt0]);
                c1[i] = u2f(bp[i * 352 + kt1]);
            }
            f32x4 sA = __builtin_amdgcn_mfma_f32_16x16x32_bf16(qf, kf0, c0, 0, 0, 0);
            f32x4 sB = __builtin_amdgcn_mfma_f32_16x16x32_bf16(qf, kf1, c1, 0, 0, 0);
            bool k1ok = (ks < 10) || (kt1 < NTOK);
#pragma unroll
            for (int i = 0; i < 4; i++) {
                float sa = sA[i];
                float sb = k1ok ? sB[i] : -1e30f;
                S0[ks][i] = sa;
                S1[ks][i] = sb;
                mx[i] = fmaxf(mx[i], fmaxf(sa, sb));
            }
        }
#pragma unroll
        for (int i = 0; i < 4; i++) {
            float v = mx[i];
            v = fmaxf(v, __shfl_xor(v, 1));
            v = fmaxf(v, __shfl_xor(v, 2));
            v = fmaxf(v, __shfl_xor(v, 4));
            v = fmaxf(v, __shfl_xor(v, 8));
            mx[i] = v;
        }

        f32x4 O0 = {}, O1 = {};
        float l[4] = {};
#pragma unroll
        for (int ks = 0; ks < 11; ks++) {
            int kbase = ks * 32;
#pragma unroll
            for (int i = 0; i < 4; i++) {
                float pa = exp2_hw(S0[ks][i] - mx[i]);   // col 2*m16   (k=m16)
                float pb = exp2_hw(S1[ks][i] - mx[i]);   // col 2*m16+1 (k=16+m16)
                l[i] += pa + pb;
                *(unsigned int*)&myP[(quad * 4 + i) * PBS + 2 * m16] = pk_bf16(pa, pb);
            }
            s16x4 plo = *(const s16x4*)&myP[m16 * PBS + quad * 8];
            s16x4 phi = *(const s16x4*)&myP[m16 * PBS + quad * 8 + 4];
            s16x8 pf  = __builtin_shufflevector(plo, phi, 0, 1, 2, 3, 4, 5, 6, 7);
            s16x8 vf0 = *(const s16x8*)&Vt[m16 * VP + kbase + quad * 8];
            s16x8 vf1 = *(const s16x8*)&Vt[(16 + m16) * VP + kbase + quad * 8];
            O0 = __builtin_amdgcn_mfma_f32_16x16x32_bf16(pf, vf0, O0, 0, 0, 0);
            O1 = __builtin_amdgcn_mfma_f32_16x16x32_bf16(pf, vf1, O1, 0, 0, 0);
        }
#pragma unroll
        for (int i = 0; i < 4; i++) {
            float v = l[i];
            v += __shfl_xor(v, 1);
            v += __shfl_xor(v, 2);
            v += __shfl_xor(v, 4);
            v += __shfl_xor(v, 8);
            l[i] = v;
        }

        int wd = w >> 4, wh = (w >> 2) & 3, wwi = w & 3;
#pragma unroll
        for (int i = 0; i < 4; i++) {
            int q = qbase + quad * 4 + i;
            if (q < NTOK) {
                float rl = __builtin_amdgcn_rcpf(l[i]);
                int qz = q / 49, qrem = q % 49, qy = qrem / 7, qx = qrem % 7;
                size_t tok = ((size_t)(wd * 7 + qz) * SIDE + (wh * 7 + qy)) * SIDE
                             + (wwi * 7 + qx);
                u16* op = oT + tok * C_DIM + h * HD;
                op[m16]      = f2b(O0[i] * rl);
                op[16 + m16] = f2b(O1[i] * rl);
            }
        }
    }
}

// ---------------------------------------------------------------------------
// Workspace: 4 x BUF + 3.24 MB weights + 2.97 MB bias plane [+ h1 tail].
// ---------------------------------------------------------------------------
extern "C" void kernel_launch(void* const* d_in, const int* in_sizes, int n_in,
                              void* d_out, int out_size, void* d_ws, size_t ws_size,
                              hipStream_t stream)
{
    const float* skip = (const float*)d_in[0];
    const float* xup  = (const float*)d_in[1];
    const float* ln1g = (const float*)d_in[5];
    const float* ln1b = (const float*)d_in[6];
    const float* kvw  = (const float*)d_in[7];
    const float* kvb  = (const float*)d_in[8];
    const float* rpb  = (const float*)d_in[9];
    const float* pw   = (const float*)d_in[10];
    const float* pb   = (const float*)d_in[11];
    const float* ln2g = (const float*)d_in[12];
    const float* ln2b = (const float*)d_in[13];
    const float* w1   = (const float*)d_in[14];
    const float* b1   = (const float*)d_in[15];
    const float* w2   = (const float*)d_in[16];
    const float* b2   = (const float*)d_in[17];
    float* out = (float*)d_out;

    char* ws = (char*)d_ws;
    const size_t BUFB = (size_t)LTOT * C_DIM * 2;   // 16,859,136 B
    const size_t WTB  = 589824 + 294912 + 1179648 + 1179648;  // 3,244,032 B
    const size_t BIASB = (size_t)NHEAD * 352 * 352 * 2;       // 2,973,696 B
    u16* skW = (u16*)(ws);
    u16* qW  = (u16*)(ws + BUFB);
    u16* Kb  = (u16*)(ws + 2 * BUFB);
    u16* Vb  = (u16*)(ws + 3 * BUFB);
    u16* oT  = (u16*)(ws);                  // overlays skW (dead)
    u16* x2  = (u16*)(ws + BUFB);           // overlays qW (dead)
    u16* lnx = (u16*)(ws + 2 * BUFB);       // overlays Kb (dead)
    char* wt = ws + 4 * BUFB;
    u16* kvWt = (u16*)(wt);
    u16* pWt  = (u16*)(wt + 589824);
    u16* w1t  = (u16*)(wt + 589824 + 294912);
    u16* w2t  = (u16*)(wt + 589824 + 294912 + 1179648);
    u16* biasPl = (u16*)(wt + WTB);
    u16* res  = (u16*)d_out;                // scratch in d_out (dead until mlp2)

    const size_t used = 4 * BUFB + WTB + BIASB;
    const size_t blkBytes = 128 * 1536 * 2;         // 393,216 B
    size_t tailCap = (ws_size > used) ? (ws_size - used) / blkBytes : 0;
    int chunkBlocks;
    u16* h1c;
    if (tailCap >= 43) {
        chunkBlocks = tailCap < 172 ? (int)tailCap : 172;
        h1c = (u16*)(ws + used);
    } else {
        chunkBlocks = 42;                            // fits in s3 (Vb, dead)
        h1c = (u16*)(ws + 3 * BUFB);
    }

    k_wt<<<dim3(6, 12), 256, 0, stream>>>(kvw, kvWt, 384, 768);
    k_wt<<<dim3(6, 6),  256, 0, stream>>>(pw,  pWt,  384, 384);
    k_wt<<<dim3(6, 24), 256, 0, stream>>>(w1,  w1t,  384, 1536);
    k_wt_pi<<<dim3(24, 6), 256, 0, stream>>>(w2, w2t, 1536, 384);
    k_bias<<<dim3(NHEAD, 352), 256, 0, stream>>>(rpb, biasPl);

    k_lnprep<<<LTOT / 4, 256, 0, stream>>>(skip, xup, ln1g, ln1b, skW, qW, res);
    k_gemm_kv<<<dim3(172, 6), 256, 0, stream>>>(skW, kvWt, kvb, Kb, Vb);
    k_attn<<<dim3(NHEAD, NWIN), 256, 0, stream>>>(qW, Kb, Vb, biasPl, oT);
    k_gemm_proj<<<dim3(343, 3), 256, 0, stream>>>(oT, pWt, pb, res, x2);
    k_ln2<<<LTOT / 4, 256, 0, stream>>>(x2, ln2g, ln2b, lnx);
    for (int b0 = 0; b0 < 172; b0 += chunkBlocks) {
        int nb = (172 - b0) < chunkBlocks ? (172 - b0) : chunkBlocks;
        int rowOfs = b0 * 128;
        int chunkRows = nb * 128;
        if (rowOfs + chunkRows > LTOT) chunkRows = LTOT - rowOfs;
        int nb64 = (chunkRows + 63) / 64;
        k_gemm_mlp1<<<dim3(nb, 12), 256, 0, stream>>>(lnx, w1t, b1, h1c, rowOfs);
        k_gemm_mlp2<<<dim3(nb64, 3), 256, 0, stream>>>(h1c, w2t, b2, x2, out, rowOfs, chunkRows);
    }
}

// Round 9
// 410.923 us; speedup vs baseline: 1.1648x; 1.0296x over previous
//
#include <hip/hip_runtime.h>
#include <hip/hip_bf16.h>
#include <cstdint>

typedef unsigned short u16;
typedef short s16x8 __attribute__((ext_vector_type(8)));
typedef short s16x4 __attribute__((ext_vector_type(4)));
typedef float f32x4 __attribute__((ext_vector_type(4)));

#define C_DIM 384
#define NHEAD 12
#define HD    32
#define NTOK  343     // tokens per window (7^3)
#define NWIN  64
#define LTOT  21952   // 28^3
#define SIDE  28

__device__ __forceinline__ float u2f(u16 u) {
    return __uint_as_float(((unsigned int)u) << 16);
}
__device__ __forceinline__ u16 f2b(float f) {
    unsigned int u = __float_as_uint(f);
    return (u16)((u + 0x7fffu + ((u >> 16) & 1u)) >> 16);   // RNE
}
__device__ __forceinline__ float exp2_hw(float x) {
    float r;
    asm("v_exp_f32 %0, %1" : "=v"(r) : "v"(x));
    return r;
}
// pack two f32 -> two bf16 (RNE) in one op
__device__ __forceinline__ unsigned int pk_bf16(float lo, float hi) {
    unsigned int r;
    asm("v_cvt_pk_bf16_f32 %0, %1, %2" : "=v"(r) : "v"(lo), "v"(hi));
    return r;
}
// gelu tanh-approx: 0.5x(1+tanh(z)) == x / (1 + 2^(-2z*log2e))
__device__ __forceinline__ float gelu_fast(float x) {
    float e = exp2_hw(-2.3022083f * (x + 0.044715f * x * x * x));
    return x * __builtin_amdgcn_rcpf(1.f + e);
}
// async global->LDS, 16 B per lane. LDS dest is wave-uniform base + lane*16.
__device__ __forceinline__ void gl16(const u16* g, u16* l) {
    __builtin_amdgcn_global_load_lds(
        (const __attribute__((address_space(1))) void*)g,
        (__attribute__((address_space(3))) void*)l, 16, 0, 0);
}

// ---------------------------------------------------------------------------
// Weight transpose + f32->bf16: Wt[n][k] = bf16(W[k][n]).  W is KxN row-major.
// ---------------------------------------------------------------------------
__global__ __launch_bounds__(256) void k_wt(
    const float* __restrict__ W, u16* __restrict__ Wt, int K, int N)
{
    __shared__ float T[64][65];
    int k0 = blockIdx.x * 64, n0 = blockIdx.y * 64;
    int t = threadIdx.x;
    int c = t & 63, rg = t >> 6;
#pragma unroll
    for (int i = 0; i < 16; i++) {
        int r = rg * 16 + i;
        T[r][c] = W[(size_t)(k0 + r) * N + n0 + c];
    }
    __syncthreads();
    int k = t & 63, ng = t >> 6;
#pragma unroll
    for (int i = 0; i < 16; i++) {
        int n = ng * 16 + i;
        Wt[(size_t)(n0 + n) * K + k0 + k] = f2b(T[k][n]);
    }
}

// Same, but the k (contraction) index is pi-permuted within each 128-block:
// j = k%128 = ct*16+n  ->  j' = 32*(ct>>1) + 2*n + (ct&1).
// Used for w2 so mlp1 can store h1 in pair-packed column order.
__global__ __launch_bounds__(256) void k_wt_pi(
    const float* __restrict__ W, u16* __restrict__ Wt, int K, int N)
{
    __shared__ float T[64][65];
    int k0 = blockIdx.x * 64, n0 = blockIdx.y * 64;
    int t = threadIdx.x;
    int c = t & 63, rg = t >> 6;
#pragma unroll
    for (int i = 0; i < 16; i++) {
        int r = rg * 16 + i;
        T[r][c] = W[(size_t)(k0 + r) * N + n0 + c];
    }
    __syncthreads();
    int k = t & 63, ng = t >> 6;
    int kg = k0 + k;
    int j = kg & 127, ct = j >> 4, nn = j & 15;
    int kp = (kg & ~127) | ((ct >> 1) << 5) | (nn << 1) | (ct & 1);
#pragma unroll
    for (int i = 0; i < 16; i++) {
        int n = ng * 16 + i;
        Wt[(size_t)(n0 + n) * K + kp] = f2b(T[k][n]);
    }
}

// ---------------------------------------------------------------------------
// Bias plane precompute: biasPl[h][q][k] = bf16(rpb[relidx(q,k)][h] * log2e).
// ---------------------------------------------------------------------------
__global__ __launch_bounds__(256) void k_bias(
    const float* __restrict__ rpb, u16* __restrict__ biasPl)
{
    int h = blockIdx.x, q = blockIdx.y;
    int qc = min(q, NTOK - 1);
    int qz = qc / 49, qrem = qc % 49, qy = qrem / 7, qx = qrem % 7;
    int cq = qz * 169 + qy * 13 + qx;
    u16* dst = biasPl + ((size_t)h * 352 + q) * 352;
    for (int k = threadIdx.x; k < 352; k += 256) {
        int kc = min(k, NTOK - 1);
        int kz = kc / 49, krem = kc % 49, ky = krem / 7, kx = krem % 7;
        int ck = kz * 169 + ky * 13 + kx;
        dst[k] = f2b(rpb[(size_t)(cq - ck + 1098) * NHEAD + h] * 1.4426950408889634f);
    }
}

// ---------------------------------------------------------------------------
// Kernel 1: dual LayerNorm + window partition -> bf16; also res = bf16(skip+xup)
// qW is consumed ONLY by attention: softmax scale baked in.
// ---------------------------------------------------------------------------
#define QSCALE 0.2550348772f

__global__ __launch_bounds__(256) void k_lnprep(
    const float* __restrict__ skip, const float* __restrict__ xup,
    const float* __restrict__ g, const float* __restrict__ bta,
    u16* __restrict__ skW, u16* __restrict__ qW, u16* __restrict__ res)
{
    int t = blockIdx.x * 4 + (threadIdx.x >> 6);
    int lane = threadIdx.x & 63;
    const float* ps = skip + (size_t)t * C_DIM;
    const float* px = xup + (size_t)t * C_DIM;
    float vs[6], vx[6];
    float s1 = 0.f, s2 = 0.f, x1 = 0.f, x2 = 0.f;
#pragma unroll
    for (int j = 0; j < 6; j++) {
        float a = ps[lane + j * 64];
        float b = px[lane + j * 64];
        vs[j] = a; vx[j] = b;
        s1 += a; s2 += a * a; x1 += b; x2 += b * b;
    }
#pragma unroll
    for (int off = 32; off; off >>= 1) {
        s1 += __shfl_xor(s1, off);
        s2 += __shfl_xor(s2, off);
        x1 += __shfl_xor(x1, off);
        x2 += __shfl_xor(x2, off);
    }
    float ms = s1 * (1.f / 384.f), mx = x1 * (1.f / 384.f);
    float rs = rsqrtf(fmaxf(s2 * (1.f / 384.f) - ms * ms, 0.f) + 1e-5f);
    float rx = rsqrtf(fmaxf(x2 * (1.f / 384.f) - mx * mx, 0.f) + 1e-5f);
    int d = t / 784, rem = t % 784, hh = rem / 28, ww = rem % 28;
    int win = (d / 7) * 16 + (hh / 7) * 4 + (ww / 7);
    int n = (d % 7) * 49 + (hh % 7) * 7 + (ww % 7);
    size_t dst = ((size_t)(win * NTOK + n)) * C_DIM + lane;
    size_t td  = (size_t)t * C_DIM + lane;
#pragma unroll
    for (int j = 0; j < 6; j++) {
        int c = lane + j * 64;
        float gg = g[c], bb = bta[c];
        skW[dst + j * 64] = f2b((vs[j] - ms) * rs * gg + bb);
        qW[dst + j * 64]  = f2b(((vx[j] - mx) * rx * gg + bb) * QSCALE);
        res[td + j * 64]  = f2b(vs[j] + vx[j]);
    }
}

// ---------------------------------------------------------------------------
// Kernel 5: LayerNorm of x2 (bf16) -> lnx (bf16).
// ---------------------------------------------------------------------------
__global__ __launch_bounds__(256) void k_ln2(
    const u16* __restrict__ x2, const float* __restrict__ g,
    const float* __restrict__ bta, u16* __restrict__ lnx)
{
    int t = blockIdx.x * 4 + (threadIdx.x >> 6);
    int lane = threadIdx.x & 63;
    const u16* p = x2 + (size_t)t * C_DIM;
    float v[6];
    float s1 = 0.f, s2 = 0.f;
#pragma unroll
    for (int j = 0; j < 6; j++) {
        float a = u2f(p[lane + j * 64]);
        v[j] = a; s1 += a; s2 += a * a;
    }
#pragma unroll
    for (int off = 32; off; off >>= 1) {
        s1 += __shfl_xor(s1, off);
        s2 += __shfl_xor(s2, off);
    }
    float m = s1 * (1.f / 384.f);
    float r = rsqrtf(fmaxf(s2 * (1.f / 384.f) - m * m, 0.f) + 1e-5f);
    size_t dst = (size_t)t * C_DIM + lane;
#pragma unroll
    for (int j = 0; j < 6; j++) {
        int c = lane + j * 64;
        lnx[dst + j * 64] = f2b((v[j] - m) * r * g[c] + bta[c]);
    }
}

// ---------------------------------------------------------------------------
// 128x128 MFMA GEMM core, global_load_lds staging (direct HBM->LDS DMA),
// double-buffered, ONE barrier per 32-K phase. BPAD=32 (no pad): the staging
// map is lane-linear (lane tid -> LDS byte tid*16), as gload_lds requires.
// Wave = 64 rows x 64 cols; per phase: 4 gl16 + 8 ds_read_b128 + 16 MFMA.
// As/Bs are [256][32]: two 128-row buffers each.
// ---------------------------------------------------------------------------
__device__ __forceinline__ void gemm128_gl(
    const u16* __restrict__ A, const u16* __restrict__ Bt, int K, int M,
    int rowBase, int colBase, int tid,
    u16 (*As)[32], u16 (*Bs)[32], f32x4 acc[4][4])
{
    const int sr  = tid >> 2;
    const int scg = (tid & 3) << 3;
    const int lane = tid & 63, wv = tid >> 6;
    const int m16 = lane & 15, quad = lane >> 4;
    const int wr = (wv >> 1) << 6, wc = (wv & 1) << 6;

    int ra0 = min(rowBase + sr, M - 1);
    int ra1 = min(rowBase + 64 + sr, M - 1);
    const u16* pa0 = A + (size_t)ra0 * K + scg;
    const u16* pa1 = A + (size_t)ra1 * K + scg;
    const u16* pb0 = Bt + (size_t)(colBase + sr) * K + scg;
    const u16* pb1 = Bt + (size_t)(colBase + 64 + sr) * K + scg;

    // wave-uniform LDS bases (each wave's 64 lanes fill a contiguous 1 KiB)
    u16* a0d = &As[0][0]  + wv * 512;
    u16* a1d = &As[64][0] + wv * 512;
    u16* b0d = &Bs[0][0]  + wv * 512;
    u16* b1d = &Bs[64][0] + wv * 512;

    gl16(pa0, a0d); gl16(pa1, a1d); gl16(pb0, b0d); gl16(pb1, b1d);
    __syncthreads();

    int buf = 0;
    for (int kk = 0; kk < K; kk += 32) {
        if (kk + 32 < K) {
            int nb = (buf ^ 1) * 4096;   // u16 offset of the other 128-row buffer
            gl16(pa0 + kk + 32, a0d + nb);
            gl16(pa1 + kk + 32, a1d + nb);
            gl16(pb0 + kk + 32, b0d + nb);
            gl16(pb1 + kk + 32, b1d + nb);
        }
        s16x8 af[4], bf[4];
#pragma unroll
        for (int rt = 0; rt < 4; rt++)
            af[rt] = *(const s16x8*)&As[buf * 128 + wr + rt * 16 + m16][quad * 8];
#pragma unroll
        for (int bt = 0; bt < 4; bt++)
            bf[bt] = *(const s16x8*)&Bs[buf * 128 + wc + bt * 16 + m16][quad * 8];
#pragma unroll
        for (int rt = 0; rt < 4; rt++)
#pragma unroll
        for (int bt = 0; bt < 4; bt++)
            acc[rt][bt] = __builtin_amdgcn_mfma_f32_16x16x32_bf16(af[rt], bf[bt], acc[rt][bt], 0, 0, 0);
        __syncthreads();
        buf ^= 1;
    }
}

// ---------------------------------------------------------------------------
// 64x128 MFMA GEMM core, global_load_lds staging, double-buffered, ONE
// barrier per 32-K phase. Wave = 64 rows x 32 cols; per phase: 3 gl16 +
// 6 ds_read_b128 + 8 MFMA. As [128][32] (2x64 rows), Bs [256][32] (2x128).
// ---------------------------------------------------------------------------
__device__ __forceinline__ void gemm64_gl(
    const u16* __restrict__ A, const u16* __restrict__ Bt, int K, int M,
    int rowBase, int colBase, int tid,
    u16 (*As)[32], u16 (*Bs)[32], f32x4 acc[4][2])
{
    const int sr  = tid >> 2;
    const int scg = (tid & 3) << 3;
    const int lane = tid & 63, wv = tid >> 6;
    const int m16 = lane & 15, quad = lane >> 4;
    const int wc = wv << 5;

    int ra = min(rowBase + sr, M - 1);
    const u16* pa  = A + (size_t)ra * K + scg;
    const u16* pb0 = Bt + (size_t)(colBase + sr) * K + scg;
    const u16* pb1 = Bt + (size_t)(colBase + 64 + sr) * K + scg;

    u16* ad  = &As[0][0]  + wv * 512;
    u16* b0d = &Bs[0][0]  + wv * 512;
    u16* b1d = &Bs[64][0] + wv * 512;

    gl16(pa, ad); gl16(pb0, b0d); gl16(pb1, b1d);
    __syncthreads();

    int buf = 0;
    for (int kk = 0; kk < K; kk += 32) {
        if (kk + 32 < K) {
            int nbA = (buf ^ 1) * 2048;  // other 64-row A buffer
            int nbB = (buf ^ 1) * 4096;  // other 128-row B buffer
            gl16(pa  + kk + 32, ad  + nbA);
            gl16(pb0 + kk + 32, b0d + nbB);
            gl16(pb1 + kk + 32, b1d + nbB);
        }
        s16x8 af[4], bf[2];
#pragma unroll
        for (int rt = 0; rt < 4; rt++)
            af[rt] = *(const s16x8*)&As[buf * 64 + rt * 16 + m16][quad * 8];
#pragma unroll
        for (int bt = 0; bt < 2; bt++)
            bf[bt] = *(const s16x8*)&Bs[buf * 128 + wc + bt * 16 + m16][quad * 8];
#pragma unroll
        for (int rt = 0; rt < 4; rt++)
#pragma unroll
        for (int bt = 0; bt < 2; bt++)
            acc[rt][bt] = __builtin_amdgcn_mfma_f32_16x16x32_bf16(af[rt], bf[bt], acc[rt][bt], 0, 0, 0);
        __syncthreads();
        buf ^= 1;
    }
}

#define EPI_SETUP \
    int lane = tid & 63, wv = tid >> 6, quad = lane >> 4, n16 = lane & 15;

// KV projection (K=384, N=768): scatter to K/V (w,head,n,d) bf16.
__global__ __launch_bounds__(256) void k_gemm_kv(
    const u16* __restrict__ A, const u16* __restrict__ Wt, const float* __restrict__ bias,
    u16* __restrict__ Kb, u16* __restrict__ Vb)
{
    __shared__ __align__(16) u16 As[256][32];
    __shared__ __align__(16) u16 Bs[256][32];
    f32x4 acc[4][4] = {};
    int tid = threadIdx.x;
    int rowBase = blockIdx.x * 128, colBase = blockIdx.y * 128;
    gemm128_gl(A, Wt, 384, LTOT, rowBase, colBase, tid, As, Bs, acc);
    EPI_SETUP
    int wr = (wv >> 1) << 6, wc = (wv & 1) << 6;
#pragma unroll
    for (int bt = 0; bt < 4; bt++) {
        int col = colBase + wc + bt * 16 + n16;
        float bcol = bias[col];
        int isv = col >= 384;
        int remc = col - (isv ? 384 : 0);
        int hh = remc >> 5, dd = remc & 31;
#pragma unroll
        for (int rt = 0; rt < 4; rt++)
#pragma unroll
        for (int reg = 0; reg < 4; reg++) {
            int r = rowBase + wr + rt * 16 + quad * 4 + reg;
            if (r < LTOT) {
                int w = r / NTOK, nn = r % NTOK;
                size_t dst = ((size_t)((w * NHEAD + hh) * NTOK + nn)) * HD + dd;
                (isv ? Vb : Kb)[dst] = f2b(acc[rt][bt][reg] + bcol);
            }
        }
    }
}

// Output projection (K=384, N=384) + bias + residual res (bf16) -> x2 bf16.
__global__ __launch_bounds__(256) void k_gemm_proj(
    const u16* __restrict__ A, const u16* __restrict__ Wt, const float* __restrict__ bias,
    const u16* __restrict__ res, u16* __restrict__ x2)
{
    __shared__ __align__(16) u16 As[128][32];
    __shared__ __align__(16) u16 Bs[256][32];
    f32x4 acc[4][2] = {};
    int tid = threadIdx.x;
    int rowBase = blockIdx.x * 64, colBase = blockIdx.y * 128;
    gemm64_gl(A, Wt, 384, LTOT, rowBase, colBase, tid, As, Bs, acc);
    EPI_SETUP
    int wc = wv << 5;
#pragma unroll
    for (int bt = 0; bt < 2; bt++) {
        int col = colBase + wc + bt * 16 + n16;
        float bcol = bias[col];
#pragma unroll
        for (int rt = 0; rt < 4; rt++)
#pragma unroll
        for (int reg = 0; reg < 4; reg++) {
            int r = rowBase + rt * 16 + quad * 4 + reg;
            if (r < LTOT) {
                size_t idx = (size_t)r * C_DIM + col;
                x2[idx] = f2b(acc[rt][bt][reg] + bcol + u2f(res[idx]));
            }
        }
    }
}

// MLP1 (K=384, N=1536) + bias + gelu -> h1 chunk bf16, pair-packed columns.
__global__ __launch_bounds__(256) void k_gemm_mlp1(
    const u16* __restrict__ A, const u16* __restrict__ Wt, const float* __restrict__ bias,
    u16* __restrict__ h1c, int rowOfs)
{
    __shared__ __align__(16) u16 As[256][32];
    __shared__ __align__(16) u16 Bs[256][32];
    f32x4 acc[4][4] = {};
    int tid = threadIdx.x;
    int rowBase = rowOfs + blockIdx.x * 128, colBase = blockIdx.y * 128;
    gemm128_gl(A, Wt, 384, LTOT, rowBase, colBase, tid, As, Bs, acc);
    EPI_SETUP
    int wr = (wv >> 1) << 6;
#pragma unroll
    for (int p2 = 0; p2 < 2; p2++) {
        int p = (wv & 1) * 2 + p2;            // global pair index 0..3
        int col0 = colBase + p * 32 + n16;    // ct = 2p
        int col1 = col0 + 16;                 // ct = 2p+1
        float bc0 = bias[col0], bc1 = bias[col1];
        int dcol = colBase + p * 32 + 2 * n16;
#pragma unroll
        for (int rt = 0; rt < 4; rt++)
#pragma unroll
        for (int reg = 0; reg < 4; reg++) {
            int r = rowBase + wr + rt * 16 + quad * 4 + reg;
            if (r < LTOT) {
                size_t rl = (size_t)(r - rowOfs);
                float v0 = gelu_fast(acc[rt][2 * p2][reg] + bc0);
                float v1 = gelu_fast(acc[rt][2 * p2 + 1][reg] + bc1);
                *(unsigned int*)&h1c[rl * 1536 + dcol] = pk_bf16(v0, v1);
            }
        }
    }
}

// MLP2 (K=1536 permuted, N=384) + bias + residual x2 (bf16) -> out f32.
// XCD sibling swizzle (full-grid case): the 3 col-blocks sharing an A-panel
// are placed at dispatch indices {v, v+8, v+16} -> same XCD, concurrent ->
// h1c re-reads hit that XCD's L2 instead of HBM.
__global__ __launch_bounds__(256) void k_gemm_mlp2(
    const u16* __restrict__ A, const u16* __restrict__ Wt, const float* __restrict__ bias,
    const u16* __restrict__ x2, float* __restrict__ out, int rowOfs, int chunkRows)
{
    __shared__ __align__(16) u16 As[128][32];
    __shared__ __align__(16) u16 Bs[256][32];
    f32x4 acc[4][2] = {};
    int tid = threadIdx.x;
    int row = blockIdx.x, col = blockIdx.y;
    if (gridDim.x == 343) {
        int v = blockIdx.y * 343 + blockIdx.x;   // dispatch index
        int g = v / 24, i = v % 24;
        if (g < 42) { row = g * 8 + (i & 7); col = i >> 3; }
        else        { row = 336 + i % 7;     col = i / 7;  }
    }
    int rowBase = row * 64, colBase = col * 128;   // local rows
    gemm64_gl(A, Wt, 1536, chunkRows, rowBase, colBase, tid, As, Bs, acc);
    EPI_SETUP
    int wc = wv << 5;
#pragma unroll
    for (int bt = 0; bt < 2; bt++) {
        int c2 = colBase + wc + bt * 16 + n16;
        float bcol = bias[c2];
#pragma unroll
        for (int rt = 0; rt < 4; rt++)
#pragma unroll
        for (int reg = 0; reg < 4; reg++) {
            int rl = rowBase + rt * 16 + quad * 4 + reg;
            int rg = rowOfs + rl;
            if (rl < chunkRows && rg < LTOT) {
                size_t idx = (size_t)rg * C_DIM + c2;
                out[idx] = acc[rt][bt][reg] + bcol + u2f(x2[idx]);
            }
        }
    }
}

// ---------------------------------------------------------------------------
// Kernel 3: MFMA flash attention (unchanged from round 8).
// K from global; bias from precomputed biasPl as MFMA C-operand; V in LDS.
// LDS: Vt 23040 + Pb 4608 = 27648 B.
// ---------------------------------------------------------------------------
#define VP  360    // Vt row stride (u16), 720 B: 16B-aligned, 8-bank spread
#define PBS 36     // Pb row stride (u16), 72 B: 8B-aligned (read as 2xb64)

__global__ __launch_bounds__(256, 2) void k_attn(
    const u16* __restrict__ qW, const u16* __restrict__ Kb, const u16* __restrict__ Vb,
    const u16* __restrict__ biasPl, u16* __restrict__ oT)
{
    __shared__ __align__(16) u16 Vt[32 * VP];        // 23040 B
    __shared__ __align__(16) u16 Pb[4 * 16 * PBS];   //  4608 B

    const int h = blockIdx.x, w = blockIdx.y;
    const int tid = threadIdx.x;
    const int lane = tid & 63, wv = tid >> 6;
    const int m16 = lane & 15, quad = lane >> 4;
    const size_t base = ((size_t)(w * NHEAD + h)) * NTOK * HD;
    const u16* Kg = Kb + base;

    // V transposed [d][col], col = 32*kb + 2*j (token kb*32+j) | +1 (token +16).
    for (int t = tid; t < 704; t += 256) {
        int dg = t / 176, rem = t - dg * 176;
        int kb = rem >> 4, j = rem & 15;
        int n0 = kb * 32 + j, n1 = n0 + 16;
        uint4 uA = make_uint4(0, 0, 0, 0), uB = make_uint4(0, 0, 0, 0);
        if (n0 < NTOK) uA = *(const uint4*)(Vb + base + n0 * HD + dg * 8);
        if (n1 < NTOK) uB = *(const uint4*)(Vb + base + n1 * HD + dg * 8);
        int d0 = dg * 8, colu = kb * 32 + 2 * j;
        unsigned int pk0 = (uA.x & 0xffffu) | (uB.x << 16);
        unsigned int pk1 = (uA.x >> 16)     | (uB.x & 0xffff0000u);
        unsigned int pk2 = (uA.y & 0xffffu) | (uB.y << 16);
        unsigned int pk3 = (uA.y >> 16)     | (uB.y & 0xffff0000u);
        unsigned int pk4 = (uA.z & 0xffffu) | (uB.z << 16);
        unsigned int pk5 = (uA.z >> 16)     | (uB.z & 0xffff0000u);
        unsigned int pk6 = (uA.w & 0xffffu) | (uB.w << 16);
        unsigned int pk7 = (uA.w >> 16)     | (uB.w & 0xffff0000u);
        *(unsigned int*)&Vt[(d0 + 0) * VP + colu] = pk0;
        *(unsigned int*)&Vt[(d0 + 1) * VP + colu] = pk1;
        *(unsigned int*)&Vt[(d0 + 2) * VP + colu] = pk2;
        *(unsigned int*)&Vt[(d0 + 3) * VP + colu] = pk3;
        *(unsigned int*)&Vt[(d0 + 4) * VP + colu] = pk4;
        *(unsigned int*)&Vt[(d0 + 5) * VP + colu] = pk5;
        *(unsigned int*)&Vt[(d0 + 6) * VP + colu] = pk6;
        *(unsigned int*)&Vt[(d0 + 7) * VP + colu] = pk7;
    }
    __syncthreads();

    u16* myP = Pb + wv * 16 * PBS;

    for (int qt = wv; qt < 22; qt += 4) {
        int qbase = qt * 16;
        int qrow = min(qbase + m16, NTOK - 1);
        s16x8 qf = *(const s16x8*)(qW + ((size_t)(w * NTOK + qrow)) * C_DIM
                                       + h * HD + quad * 8);
        const u16* bp = biasPl + ((size_t)h * 352 + qbase + quad * 4) * 352;

        f32x4 S0[11], S1[11];
        float mx[4] = {-1e30f, -1e30f, -1e30f, -1e30f};

#pragma unroll
        for (int ks = 0; ks < 11; ks++) {
            int kbase = ks * 32;
            int kt0 = kbase + m16, kt1 = kt0 + 16;
            s16x8 kf0 = *(const s16x8*)(Kg + (size_t)kt0 * HD + quad * 8);
            s16x8 kf1 = *(const s16x8*)(Kg + (size_t)kt1 * HD + quad * 8);
            f32x4 c0, c1;
#pragma unroll
            for (int i = 0; i < 4; i++) {
                c0[i] = u2f(bp[i * 352 + kt0]);
                c1[i] = u2f(bp[i * 352 + kt1]);
            }
            f32x4 sA = __builtin_amdgcn_mfma_f32_16x16x32_bf16(qf, kf0, c0, 0, 0, 0);
            f32x4 sB = __builtin_amdgcn_mfma_f32_16x16x32_bf16(qf, kf1, c1, 0, 0, 0);
            bool k1ok = (ks < 10) || (kt1 < NTOK);
#pragma unroll
            for (int i = 0; i < 4; i++) {
                float sa = sA[i];
                float sb = k1ok ? sB[i] : -1e30f;
                S0[ks][i] = sa;
                S1[ks][i] = sb;
                mx[i] = fmaxf(mx[i], fmaxf(sa, sb));
            }
        }
#pragma unroll
        for (int i = 0; i < 4; i++) {
            float v = mx[i];
            v = fmaxf(v, __shfl_xor(v, 1));
            v = fmaxf(v, __shfl_xor(v, 2));
            v = fmaxf(v, __shfl_xor(v, 4));
            v = fmaxf(v, __shfl_xor(v, 8));
            mx[i] = v;
        }

        f32x4 O0 = {}, O1 = {};
        float l[4] = {};
#pragma unroll
        for (int ks = 0; ks < 11; ks++) {
            int kbase = ks * 32;
#pragma unroll
            for (int i = 0; i < 4; i++) {
                float pa = exp2_hw(S0[ks][i] - mx[i]);   // col 2*m16   (k=m16)
                float pb = exp2_hw(S1[ks][i] - mx[i]);   // col 2*m16+1 (k=16+m16)
                l[i] += pa + pb;
                *(unsigned int*)&myP[(quad * 4 + i) * PBS + 2 * m16] = pk_bf16(pa, pb);
            }
            s16x4 plo = *(const s16x4*)&myP[m16 * PBS + quad * 8];
            s16x4 phi = *(const s16x4*)&myP[m16 * PBS + quad * 8 + 4];
            s16x8 pf  = __builtin_shufflevector(plo, phi, 0, 1, 2, 3, 4, 5, 6, 7);
            s16x8 vf0 = *(const s16x8*)&Vt[m16 * VP + kbase + quad * 8];
            s16x8 vf1 = *(const s16x8*)&Vt[(16 + m16) * VP + kbase + quad * 8];
            O0 = __builtin_amdgcn_mfma_f32_16x16x32_bf16(pf, vf0, O0, 0, 0, 0);
            O1 = __builtin_amdgcn_mfma_f32_16x16x32_bf16(pf, vf1, O1, 0, 0, 0);
        }
#pragma unroll
        for (int i = 0; i < 4; i++) {
            float v = l[i];
            v += __shfl_xor(v, 1);
            v += __shfl_xor(v, 2);
            v += __shfl_xor(v, 4);
            v += __shfl_xor(v, 8);
            l[i] = v;
        }

        int wd = w >> 4, wh = (w >> 2) & 3, wwi = w & 3;
#pragma unroll
        for (int i = 0; i < 4; i++) {
            int q = qbase + quad * 4 + i;
            if (q < NTOK) {
                float rl = __builtin_amdgcn_rcpf(l[i]);
                int qz = q / 49, qrem = q % 49, qy = qrem / 7, qx = qrem % 7;
                size_t tok = ((size_t)(wd * 7 + qz) * SIDE + (wh * 7 + qy)) * SIDE
                             + (wwi * 7 + qx);
                u16* op = oT + tok * C_DIM + h * HD;
                op[m16]      = f2b(O0[i] * rl);
                op[16 + m16] = f2b(O1[i] * rl);
            }
        }
    }
}

// ---------------------------------------------------------------------------
// Workspace: 4 x BUF + 3.24 MB weights + 2.97 MB bias plane [+ h1 tail].
// ---------------------------------------------------------------------------
extern "C" void kernel_launch(void* const* d_in, const int* in_sizes, int n_in,
                              void* d_out, int out_size, void* d_ws, size_t ws_size,
                              hipStream_t stream)
{
    const float* skip = (const float*)d_in[0];
    const float* xup  = (const float*)d_in[1];
    const float* ln1g = (const float*)d_in[5];
    const float* ln1b = (const float*)d_in[6];
    const float* kvw  = (const float*)d_in[7];
    const float* kvb  = (const float*)d_in[8];
    const float* rpb  = (const float*)d_in[9];
    const float* pw   = (const float*)d_in[10];
    const float* pb   = (const float*)d_in[11];
    const float* ln2g = (const float*)d_in[12];
    const float* ln2b = (const float*)d_in[13];
    const float* w1   = (const float*)d_in[14];
    const float* b1   = (const float*)d_in[15];
    const float* w2   = (const float*)d_in[16];
    const float* b2   = (const float*)d_in[17];
    float* out = (float*)d_out;

    char* ws = (char*)d_ws;
    const size_t BUFB = (size_t)LTOT * C_DIM * 2;   // 16,859,136 B
    const size_t WTB  = 589824 + 294912 + 1179648 + 1179648;  // 3,244,032 B
    const size_t BIASB = (size_t)NHEAD * 352 * 352 * 2;       // 2,973,696 B
    u16* skW = (u16*)(ws);
    u16* qW  = (u16*)(ws + BUFB);
    u16* Kb  = (u16*)(ws + 2 * BUFB);
    u16* Vb  = (u16*)(ws + 3 * BUFB);
    u16* oT  = (u16*)(ws);                  // overlays skW (dead)
    u16* x2  = (u16*)(ws + BUFB);           // overlays qW (dead)
    u16* lnx = (u16*)(ws + 2 * BUFB);       // overlays Kb (dead)
    char* wt = ws + 4 * BUFB;
    u16* kvWt = (u16*)(wt);
    u16* pWt  = (u16*)(wt + 589824);
    u16* w1t  = (u16*)(wt + 589824 + 294912);
    u16* w2t  = (u16*)(wt + 589824 + 294912 + 1179648);
    u16* biasPl = (u16*)(wt + WTB);
    u16* res  = (u16*)d_out;                // scratch in d_out (dead until mlp2)

    const size_t used = 4 * BUFB + WTB + BIASB;
    const size_t blkBytes = 128 * 1536 * 2;         // 393,216 B
    size_t tailCap = (ws_size > used) ? (ws_size - used) / blkBytes : 0;
    int chunkBlocks;
    u16* h1c;
    if (tailCap >= 43) {
        chunkBlocks = tailCap < 172 ? (int)tailCap : 172;
        h1c = (u16*)(ws + used);
    } else {
        chunkBlocks = 42;                            // fits in s3 (Vb, dead)
        h1c = (u16*)(ws + 3 * BUFB);
    }

    k_wt<<<dim3(6, 12), 256, 0, stream>>>(kvw, kvWt, 384, 768);
    k_wt<<<dim3(6, 6),  256, 0, stream>>>(pw,  pWt,  384, 384);
    k_wt<<<dim3(6, 24), 256, 0, stream>>>(w1,  w1t,  384, 1536);
    k_wt_pi<<<dim3(24, 6), 256, 0, stream>>>(w2, w2t, 1536, 384);
    k_bias<<<dim3(NHEAD, 352), 256, 0, stream>>>(rpb, biasPl);

    k_lnprep<<<LTOT / 4, 256, 0, stream>>>(skip, xup, ln1g, ln1b, skW, qW, res);
    k_gemm_kv<<<dim3(172, 6), 256, 0, stream>>>(skW, kvWt, kvb, Kb, Vb);
    k_attn<<<dim3(NHEAD, NWIN), 256, 0, stream>>>(qW, Kb, Vb, biasPl, oT);
    k_gemm_proj<<<dim3(343, 3), 256, 0, stream>>>(oT, pWt, pb, res, x2);
    k_ln2<<<LTOT / 4, 256, 0, stream>>>(x2, ln2g, ln2b, lnx);
    for (int b0 = 0; b0 < 172; b0 += chunkBlocks) {
        int nb = (172 - b0) < chunkBlocks ? (172 - b0) : chunkBlocks;
        int rowOfs = b0 * 128;
        int chunkRows = nb * 128;
        if (rowOfs + chunkRows > LTOT) chunkRows = LTOT - rowOfs;
        int nb64 = (chunkRows + 63) / 64;
        k_gemm_mlp1<<<dim3(nb, 12), 256, 0, stream>>>(lnx, w1t, b1, h1c, rowOfs);
        k_gemm_mlp2<<<dim3(nb64, 3), 256, 0, stream>>>(h1c, w2t, b2, x2, out, rowOfs, chunkRows);
    }
}